// Round 9
// baseline (797.883 us; speedup 1.0000x reference)
//
#include <hip/hip_runtime.h>
#include <hip/hip_bf16.h>

using bf16x8 = __attribute__((ext_vector_type(8))) short;
using f32x4  = __attribute__((ext_vector_type(4))) float;

#define NTOK 8192
#define DDIM 1024
#define NEXP 8
#define HDIM 4096
#define CAP  17408   // 16384 pairs + 8*128 padding
#define MT   136     // CAP / 128 M-tiles (worst case)
#define BK   64

struct Ctrl {
  unsigned cnt[8];
  unsigned cursor[8];
  unsigned off[9];
  unsigned used_end;
  float imp[8];
  float loadsum[8];
  float validcnt;
};

typedef __attribute__((address_space(1))) unsigned GU;
typedef __attribute__((address_space(3))) unsigned LU;
__device__ __forceinline__ void gl_lds16(const unsigned short* g, short* l) {
  __builtin_amdgcn_global_load_lds((const GU*)(g), (LU*)(l), 16, 0, 0);
}

__device__ inline unsigned short f2bfu(float f) {
  __hip_bfloat16 h = __float2bfloat16(f);
  return *reinterpret_cast<unsigned short*>(&h);
}
__device__ inline bf16x8 cvt8(float4 a, float4 b) {
  bf16x8 v;
  v[0] = (short)f2bfu(a.x); v[1] = (short)f2bfu(a.y);
  v[2] = (short)f2bfu(a.z); v[3] = (short)f2bfu(a.w);
  v[4] = (short)f2bfu(b.x); v[5] = (short)f2bfu(b.y);
  v[6] = (short)f2bfu(b.z); v[7] = (short)f2bfu(b.w);
  return v;
}

// ---------------- Router: logits -> softmax -> top2 -> stats; also x -> bf16 ----------------
__global__ __launch_bounds__(256) void router_kernel(
    const float* __restrict__ x, const int* __restrict__ mask,
    const float* __restrict__ rw, Ctrl* __restrict__ ctrl,
    int* __restrict__ top2i, float* __restrict__ top2w,
    unsigned short* __restrict__ xb)
{
  __shared__ float s_imp[8];
  __shared__ float s_load[8];
  __shared__ unsigned s_cnt[8];
  __shared__ unsigned s_valid;
  if (threadIdx.x < 8) { s_imp[threadIdx.x] = 0.f; s_load[threadIdx.x] = 0.f; s_cnt[threadIdx.x] = 0u; }
  if (threadIdx.x == 0) s_valid = 0u;
  __syncthreads();

  int wid = threadIdx.x >> 6, lane = threadIdx.x & 63;

  for (int token = blockIdx.x * 4 + wid; token < NTOK; token += gridDim.x * 4) {
    const float* xr = x + (size_t)token * DDIM + lane * 16;
    float4 x0 = ((const float4*)xr)[0];
    float4 x1 = ((const float4*)xr)[1];
    float4 x2 = ((const float4*)xr)[2];
    float4 x3 = ((const float4*)xr)[3];

    unsigned short* xo = xb + (size_t)token * DDIM + lane * 16;
    *(bf16x8*)xo       = cvt8(x0, x1);
    *(bf16x8*)(xo + 8) = cvt8(x2, x3);

    float s[8];
    #pragma unroll
    for (int e = 0; e < 8; ++e) {
      const float* rp = rw + e * DDIM + lane * 16;
      float4 r0 = ((const float4*)rp)[0];
      float4 r1 = ((const float4*)rp)[1];
      float4 r2 = ((const float4*)rp)[2];
      float4 r3 = ((const float4*)rp)[3];
      float a = x0.x * r0.x;
      a = fmaf(x0.y, r0.y, a); a = fmaf(x0.z, r0.z, a); a = fmaf(x0.w, r0.w, a);
      a = fmaf(x1.x, r1.x, a); a = fmaf(x1.y, r1.y, a); a = fmaf(x1.z, r1.z, a); a = fmaf(x1.w, r1.w, a);
      a = fmaf(x2.x, r2.x, a); a = fmaf(x2.y, r2.y, a); a = fmaf(x2.z, r2.z, a); a = fmaf(x2.w, r2.w, a);
      a = fmaf(x3.x, r3.x, a); a = fmaf(x3.y, r3.y, a); a = fmaf(x3.z, r3.z, a); a = fmaf(x3.w, r3.w, a);
      s[e] = a;
    }
    #pragma unroll
    for (int e = 0; e < 8; ++e)
      #pragma unroll
      for (int o = 32; o; o >>= 1) s[e] += __shfl_xor(s[e], o);

    if (lane == 0) {
      float mx = s[0];
      #pragma unroll
      for (int e = 1; e < 8; ++e) mx = fmaxf(mx, s[e]);
      float p[8], sum = 0.f;
      #pragma unroll
      for (int e = 0; e < 8; ++e) { p[e] = __expf(s[e] - mx); sum += p[e]; }
      float inv = 1.0f / sum;
      #pragma unroll
      for (int e = 0; e < 8; ++e) p[e] *= inv;
      int i1 = 0;
      #pragma unroll
      for (int e = 1; e < 8; ++e) if (p[e] > p[i1]) i1 = e;
      int i2 = (i1 == 0) ? 1 : 0;
      #pragma unroll
      for (int e = 0; e < 8; ++e) if (e != i1 && p[e] > p[i2]) i2 = e;
      float denom = p[i1] + p[i2] + 1e-9f;
      top2i[2 * token] = i1;            top2i[2 * token + 1] = i2;
      top2w[2 * token] = p[i1] / denom; top2w[2 * token + 1] = p[i2] / denom;
      if (mask[token]) {
        #pragma unroll
        for (int e = 0; e < 8; ++e) atomicAdd(&s_imp[e], p[e]);
        atomicAdd(&s_load[i1], 1.0f);
        atomicAdd(&s_cnt[i1], 1u);
        atomicAdd(&s_cnt[i2], 1u);
        atomicAdd(&s_valid, 1u);
      }
    }
  }
  __syncthreads();
  if (threadIdx.x < 8) {
    if (s_imp[threadIdx.x] != 0.f)  atomicAdd(&ctrl->imp[threadIdx.x], s_imp[threadIdx.x]);
    if (s_load[threadIdx.x] != 0.f) atomicAdd(&ctrl->loadsum[threadIdx.x], s_load[threadIdx.x]);
    if (s_cnt[threadIdx.x])         atomicAdd(&ctrl->cnt[threadIdx.x], s_cnt[threadIdx.x]);
  }
  if (threadIdx.x == 0 && s_valid) atomicAdd(&ctrl->validcnt, (float)s_valid);
}

// ---------------- Offsets (128-aligned segments) + aux loss ----------------
__global__ void finalize_kernel(Ctrl* __restrict__ c, float* __restrict__ auxout)
{
  unsigned o = 0;
  for (int e = 0; e < 8; ++e) { c->off[e] = o; o += (c->cnt[e] + 127u) & ~127u; }
  c->off[8] = o;
  c->used_end = o;
  float cn = fmaxf(c->validcnt, 1.0f);
  float aux = 0.f;
  for (int e = 0; e < 8; ++e) aux += c->imp[e] * c->loadsum[e];
  auxout[0] = aux * 8.0f / (cn * cn);
}

// ---------------- Scatter pairs into per-expert segments ----------------
__global__ __launch_bounds__(256) void scatter_kernel(
    const int* __restrict__ mask, Ctrl* __restrict__ ctrl,
    const int* __restrict__ top2i, const float* __restrict__ top2w,
    int* __restrict__ ptok, float* __restrict__ pwv)
{
  __shared__ unsigned s_cnt[8], s_base[8], s_cur[8];
  if (threadIdx.x < 8) { s_cnt[threadIdx.x] = 0u; s_cur[threadIdx.x] = 0u; }
  __syncthreads();

  int token = blockIdx.x * 256 + threadIdx.x;
  int e0 = -1, e1 = -1; float w0 = 0.f, w1v = 0.f;
  bool valid = (token < NTOK) && mask[token];
  if (valid) {
    e0 = top2i[2 * token];     w0  = top2w[2 * token];
    e1 = top2i[2 * token + 1]; w1v = top2w[2 * token + 1];
    atomicAdd(&s_cnt[e0], 1u);
    atomicAdd(&s_cnt[e1], 1u);
  }
  __syncthreads();
  if (threadIdx.x < 8 && s_cnt[threadIdx.x])
    s_base[threadIdx.x] = ctrl->off[threadIdx.x] +
                          atomicAdd(&ctrl->cursor[threadIdx.x], s_cnt[threadIdx.x]);
  __syncthreads();
  if (valid) {
    unsigned p0 = atomicAdd(&s_cur[e0], 1u);
    unsigned row0 = s_base[e0] + p0;
    ptok[row0] = token; pwv[row0] = w0;
    unsigned p1 = atomicAdd(&s_cur[e1], 1u);
    unsigned row1 = s_base[e1] + p1;
    ptok[row1] = token; pwv[row1] = w1v;
  }
}

// ---------------- Weight chunk converters (fp32 -> bf16, each elem once) ----------------
__global__ __launch_bounds__(256) void convert_w1_kernel(
    const float* __restrict__ src, unsigned short* __restrict__ dst, int hoff, int HC)
{
  unsigned n = (unsigned)NEXP * HC * DDIM;
  unsigned step = gridDim.x * 256 * 8;
  unsigned chsz = (unsigned)HC * DDIM;
  for (unsigned flat = (blockIdx.x * 256 + threadIdx.x) * 8; flat < n; flat += step) {
    unsigned e = flat / chsz;
    const float* s = src + (size_t)flat + (size_t)e * (HDIM - HC) * DDIM + (size_t)hoff * DDIM;
    float4 v0 = ((const float4*)s)[0];
    float4 v1 = ((const float4*)s)[1];
    *(bf16x8*)&dst[flat] = cvt8(v0, v1);
  }
}

__global__ __launch_bounds__(256) void convert_w2_kernel(
    const float* __restrict__ src, unsigned short* __restrict__ dst, int hoff, int HC)
{
  unsigned n = (unsigned)NEXP * DDIM * HC;
  unsigned step = gridDim.x * 256 * 8;
  for (unsigned flat = (blockIdx.x * 256 + threadIdx.x) * 8; flat < n; flat += step) {
    unsigned row = flat / (unsigned)HC;
    const float* s = src + (size_t)flat + (size_t)row * (HDIM - HC) + hoff;
    float4 v0 = ((const float4*)s)[0];
    float4 v1 = ((const float4*)s)[1];
    *(bf16x8*)&dst[flat] = cvt8(v0, v1);
  }
}

// ======== 128x128 tile, BK=64, 4 waves — R7 structure + 5 blocks/CU ========
// LDS [128 rows][64 cols] bf16 per operand (16KB each, 32KB total -> 5 blocks/CU).
// __launch_bounds__(256,5) caps VGPR at 102 (we use ~92) so occupancy is
// LDS-limited at 5 blocks/CU; implicit wave-level overlap (m114) hides the
// per-tile vmcnt drain.

#define STAGE8(kt) { \
  _Pragma("unroll") \
  for (int i = 0; i < 4; ++i) { \
    gl_lds16(aRp[i] + (size_t)(kt) * BK, &As[(i * 32 + w * 8) * 64]); \
    gl_lds16(bRp[i] + (size_t)(kt) * BK, &Bs[(i * 32 + w * 8) * 64]); \
  } }

#define KSTEP() { \
  _Pragma("unroll") \
  for (int kk = 0; kk < 2; ++kk) { \
    int rdc = kk ? rd1 : rd0; \
    bf16x8 af[4], bfv[4]; \
    _Pragma("unroll") \
    for (int mi = 0; mi < 4; ++mi) \
      af[mi] = *(const bf16x8*)&As[(wm * 64 + mi * 16 + rl) * 64 + rdc]; \
    _Pragma("unroll") \
    for (int ni = 0; ni < 4; ++ni) \
      bfv[ni] = *(const bf16x8*)&Bs[(wn * 64 + ni * 16 + rl) * 64 + rdc]; \
    _Pragma("unroll") \
    for (int mi = 0; mi < 4; ++mi) \
      _Pragma("unroll") \
      for (int ni = 0; ni < 4; ++ni) \
        acc[mi][ni] = __builtin_amdgcn_mfma_f32_16x16x32_bf16(af[mi], bfv[ni], acc[mi][ni], 0, 0, 0); \
  } }

// ---------------- fc1: H = silu(gather(xb) @ w1b^T + b1) -> bf16 ----------------
__global__ __launch_bounds__(256, 5) void fc1_kernel(
    const unsigned short* __restrict__ xb, const unsigned short* __restrict__ w1b,
    const float* __restrict__ b1, const int* __restrict__ ptok,
    const Ctrl* __restrict__ ctrl, unsigned short* __restrict__ Hbuf,
    int hoff, int HC)
{
  __shared__ __align__(16) short As[8192];
  __shared__ __align__(16) short Bs[8192];

  int nwg = gridDim.x * gridDim.y;
  int id  = blockIdx.y * gridDim.x + blockIdx.x;
  int cpx = nwg >> 3;
  int swz = (id & 7) * cpx + (id >> 3);
  int bx = swz % gridDim.x, by = swz / gridDim.x;

  int m0 = by * 128;
  if ((unsigned)m0 >= ctrl->used_end) return;
  int e = 0;
  #pragma unroll
  for (int i = 1; i < 8; ++i) if ((unsigned)m0 >= ctrl->off[i]) e = i;

  int n0 = bx * 128;
  int t = threadIdx.x, w = t >> 6, l = t & 63;
  int lrow = l >> 3;                         // 0..7
  int sc8 = ((l & 7) ^ lrow) * 8;            // pre-swizzled source chunk (shorts)

  const unsigned short* aRp[4];
  const unsigned short* bRp[4];
  #pragma unroll
  for (int i = 0; i < 4; ++i) {
    int r = i * 32 + w * 8 + lrow;
    int tok = ptok[m0 + r]; if (tok < 0) tok = 0;
    aRp[i] = xb + (size_t)tok * DDIM + sc8;
    bRp[i] = w1b + ((size_t)e * HC + n0 + r) * DDIM + sc8;
  }

  int wm = w >> 1, wn = w & 1, kc = l >> 4, rl = l & 15;
  int rd0 = ((kc)     ^ (rl & 7)) * 8;       // kk=0 read chunk
  int rd1 = ((4 + kc) ^ (rl & 7)) * 8;       // kk=1

  f32x4 acc[4][4] = {};
  const int NK = DDIM / BK;                  // 16

  for (int kt = 0; kt < NK; ++kt) {
    STAGE8(kt);
    __syncthreads();                         // drain -> LDS ready
    KSTEP();
    __syncthreads();                         // reads done before next overwrite
  }

  float b1v[4];
  #pragma unroll
  for (int ni = 0; ni < 4; ++ni)
    b1v[ni] = b1[e * HDIM + hoff + n0 + wn * 64 + ni * 16 + rl];

  #pragma unroll
  for (int mi = 0; mi < 4; ++mi) {
    #pragma unroll
    for (int reg = 0; reg < 4; ++reg) {
      int grow = m0 + wm * 64 + mi * 16 + kc * 4 + reg;
      size_t base = (size_t)grow * HC;
      #pragma unroll
      for (int ni = 0; ni < 4; ++ni) {
        int col = n0 + wn * 64 + ni * 16 + rl;
        float v = acc[mi][ni][reg] + b1v[ni];
        v = v / (1.0f + __expf(-v));
        Hbuf[base + col] = f2bfu(v);
      }
    }
  }
}

// ---------------- fc2: y += w * (Hbuf @ w2b^T + b2), K-split x2 ----------------
__global__ __launch_bounds__(256, 5) void fc2_kernel(
    const unsigned short* __restrict__ Hbuf, const unsigned short* __restrict__ w2b,
    const float* __restrict__ b2, const int* __restrict__ ptok,
    const float* __restrict__ pwv, const Ctrl* __restrict__ ctrl,
    float* __restrict__ y, int hoff, int HC)
{
  __shared__ __align__(16) short As[8192];
  __shared__ __align__(16) short Bs[8192];

  int nwg = gridDim.x * gridDim.y;
  int id  = blockIdx.y * gridDim.x + blockIdx.x;
  int cpx = nwg >> 3;
  int swz = (id & 7) * cpx + (id >> 3);
  int bx = swz % gridDim.x, by = swz / gridDim.x;

  int ntile = bx & 7, kz = bx >> 3;          // gridDim.x = 16: 8 N-tiles x 2 K-splits
  int KLEN = HC >> 1;
  int ksoff = kz * KLEN;

  int m0 = by * 128;
  if ((unsigned)m0 >= ctrl->used_end) return;
  int e = 0;
  #pragma unroll
  for (int i = 1; i < 8; ++i) if ((unsigned)m0 >= ctrl->off[i]) e = i;

  int n0 = ntile * 128;
  int t = threadIdx.x, w = t >> 6, l = t & 63;
  int lrow = l >> 3;
  int sc8 = ((l & 7) ^ lrow) * 8;

  const unsigned short* aRp[4];
  const unsigned short* bRp[4];
  #pragma unroll
  for (int i = 0; i < 4; ++i) {
    int r = i * 32 + w * 8 + lrow;
    aRp[i] = Hbuf + (size_t)(m0 + r) * HC + ksoff + sc8;
    bRp[i] = w2b + ((size_t)e * DDIM + n0 + r) * HC + ksoff + sc8;
  }

  int wm = w >> 1, wn = w & 1, kc = l >> 4, rl = l & 15;
  int rd0 = ((kc)     ^ (rl & 7)) * 8;
  int rd1 = ((4 + kc) ^ (rl & 7)) * 8;

  f32x4 acc[4][4] = {};
  const int NK = KLEN / BK;                  // HC=4096 -> 32

  for (int kt = 0; kt < NK; ++kt) {
    STAGE8(kt);
    __syncthreads();
    KSTEP();
    __syncthreads();
  }

  bool addb = (hoff == 0) && (kz == 0);
  float b2v[4];
  #pragma unroll
  for (int ni = 0; ni < 4; ++ni)
    b2v[ni] = addb ? b2[e * DDIM + n0 + wn * 64 + ni * 16 + rl] : 0.0f;

  #pragma unroll
  for (int mi = 0; mi < 4; ++mi) {
    #pragma unroll
    for (int reg = 0; reg < 4; ++reg) {
      int grow = m0 + wm * 64 + mi * 16 + kc * 4 + reg;
      int tok = ptok[grow];
      if (tok < 0) continue;
      float wgt = pwv[grow];
      float* yrow = y + (size_t)tok * DDIM;
      #pragma unroll
      for (int ni = 0; ni < 4; ++ni) {
        int col = n0 + wn * 64 + ni * 16 + rl;
        atomicAdd(&yrow[col], wgt * (acc[mi][ni][reg] + b2v[ni]));
      }
    }
  }
}

extern "C" void kernel_launch(void* const* d_in, const int* in_sizes, int n_in,
                              void* d_out, int out_size, void* d_ws, size_t ws_size,
                              hipStream_t stream) {
  (void)in_sizes; (void)n_in;
  const float* xp   = (const float*)d_in[0];
  const int*   mkp  = (const int*)d_in[1];
  const float* rwp  = (const float*)d_in[2];
  const float* w1p  = (const float*)d_in[3];
  const float* b1p  = (const float*)d_in[4];
  const float* w2p  = (const float*)d_in[5];
  const float* b2p  = (const float*)d_in[6];

  float* yp   = (float*)d_out;
  float* auxp = (float*)d_out + (out_size - 1);

  char* wsb = (char*)d_ws;
  Ctrl* ctrl = (Ctrl*)wsb;
  int*   top2i = (int*)(wsb + 1024);
  float* top2w = (float*)(wsb + 66560);
  int*   ptok  = (int*)(wsb + 132096);
  float* pwv   = (float*)(wsb + 205824);
  unsigned short* xb   = (unsigned short*)(wsb + 1048576);   // 16 MB
  unsigned short* Wbuf = (unsigned short*)(wsb + 17825792);  // 16384*HC bytes

  // HC ladder: peak ws = 17825792 + 16384*HC (Wbuf) + 34816*HC (Hbuf)
  int HC = 4096;
  while (HC > 1024 && ws_size < 17825792ull + 51200ull * (unsigned long long)HC) HC >>= 1;
  int nch = HDIM / HC;
  unsigned short* Hbuf = (unsigned short*)(wsb + 17825792 + (size_t)16384 * HC);

  hipMemsetAsync(d_out, 0, (size_t)out_size * sizeof(float), stream);
  hipMemsetAsync(ctrl, 0, 256, stream);
  hipMemsetAsync(ptok, 0xFF, CAP * sizeof(int), stream);

  router_kernel<<<1024, 256, 0, stream>>>(xp, mkp, rwp, ctrl, top2i, top2w, xb);
  finalize_kernel<<<1, 1, 0, stream>>>(ctrl, auxp);
  scatter_kernel<<<NTOK / 256, 256, 0, stream>>>(mkp, ctrl, top2i, top2w, ptok, pwv);

  for (int c = 0; c < nch; ++c) {
    int hoff = c * HC;
    convert_w1_kernel<<<2048, 256, 0, stream>>>(w1p, Wbuf, hoff, HC);
    fc1_kernel<<<dim3(HC / 128, MT), 256, 0, stream>>>(xb, Wbuf, b1p, ptok, ctrl, Hbuf, hoff, HC);
    convert_w2_kernel<<<2048, 256, 0, stream>>>(w2p, Wbuf, hoff, HC);
    fc2_kernel<<<dim3(16, MT), 256, 0, stream>>>(Hbuf, Wbuf, b2p, ptok, pwv, ctrl, yp, hoff, HC);
  }
}

// Round 10
// 721.574 us; speedup vs baseline: 1.1058x; 1.1058x over previous
//
#include <hip/hip_runtime.h>
#include <hip/hip_bf16.h>

using bf16x8 = __attribute__((ext_vector_type(8))) short;
using f32x4  = __attribute__((ext_vector_type(4))) float;

#define NTOK 8192
#define DDIM 1024
#define NEXP 8
#define HDIM 4096
#define CAP  17408   // 16384 pairs + 8*128 padding
#define MT   136     // CAP / 128 M-tiles (worst case)
#define BK   64

struct Ctrl {
  unsigned cnt[8];
  unsigned cursor[8];
  unsigned off[9];
  unsigned used_end;
  float imp[8];
  float loadsum[8];
  float validcnt;
};

typedef __attribute__((address_space(1))) unsigned GU;
typedef __attribute__((address_space(3))) unsigned LU;
__device__ __forceinline__ void gl_lds16(const unsigned short* g, short* l) {
  __builtin_amdgcn_global_load_lds((const GU*)(g), (LU*)(l), 16, 0, 0);
}

__device__ inline unsigned short f2bfu(float f) {
  __hip_bfloat16 h = __float2bfloat16(f);
  return *reinterpret_cast<unsigned short*>(&h);
}
__device__ inline bf16x8 cvt8(float4 a, float4 b) {
  bf16x8 v;
  v[0] = (short)f2bfu(a.x); v[1] = (short)f2bfu(a.y);
  v[2] = (short)f2bfu(a.z); v[3] = (short)f2bfu(a.w);
  v[4] = (short)f2bfu(b.x); v[5] = (short)f2bfu(b.y);
  v[6] = (short)f2bfu(b.z); v[7] = (short)f2bfu(b.w);
  return v;
}

// ---------------- Router: logits -> softmax -> top2 -> stats; also x -> bf16 ----------------
__global__ __launch_bounds__(256) void router_kernel(
    const float* __restrict__ x, const int* __restrict__ mask,
    const float* __restrict__ rw, Ctrl* __restrict__ ctrl,
    int* __restrict__ top2i, float* __restrict__ top2w,
    unsigned short* __restrict__ xb)
{
  __shared__ float s_imp[8];
  __shared__ float s_load[8];
  __shared__ unsigned s_cnt[8];
  __shared__ unsigned s_valid;
  if (threadIdx.x < 8) { s_imp[threadIdx.x] = 0.f; s_load[threadIdx.x] = 0.f; s_cnt[threadIdx.x] = 0u; }
  if (threadIdx.x == 0) s_valid = 0u;
  __syncthreads();

  int wid = threadIdx.x >> 6, lane = threadIdx.x & 63;

  for (int token = blockIdx.x * 4 + wid; token < NTOK; token += gridDim.x * 4) {
    const float* xr = x + (size_t)token * DDIM + lane * 16;
    float4 x0 = ((const float4*)xr)[0];
    float4 x1 = ((const float4*)xr)[1];
    float4 x2 = ((const float4*)xr)[2];
    float4 x3 = ((const float4*)xr)[3];

    unsigned short* xo = xb + (size_t)token * DDIM + lane * 16;
    *(bf16x8*)xo       = cvt8(x0, x1);
    *(bf16x8*)(xo + 8) = cvt8(x2, x3);

    float s[8];
    #pragma unroll
    for (int e = 0; e < 8; ++e) {
      const float* rp = rw + e * DDIM + lane * 16;
      float4 r0 = ((const float4*)rp)[0];
      float4 r1 = ((const float4*)rp)[1];
      float4 r2 = ((const float4*)rp)[2];
      float4 r3 = ((const float4*)rp)[3];
      float a = x0.x * r0.x;
      a = fmaf(x0.y, r0.y, a); a = fmaf(x0.z, r0.z, a); a = fmaf(x0.w, r0.w, a);
      a = fmaf(x1.x, r1.x, a); a = fmaf(x1.y, r1.y, a); a = fmaf(x1.z, r1.z, a); a = fmaf(x1.w, r1.w, a);
      a = fmaf(x2.x, r2.x, a); a = fmaf(x2.y, r2.y, a); a = fmaf(x2.z, r2.z, a); a = fmaf(x2.w, r2.w, a);
      a = fmaf(x3.x, r3.x, a); a = fmaf(x3.y, r3.y, a); a = fmaf(x3.z, r3.z, a); a = fmaf(x3.w, r3.w, a);
      s[e] = a;
    }
    #pragma unroll
    for (int e = 0; e < 8; ++e)
      #pragma unroll
      for (int o = 32; o; o >>= 1) s[e] += __shfl_xor(s[e], o);

    if (lane == 0) {
      float mx = s[0];
      #pragma unroll
      for (int e = 1; e < 8; ++e) mx = fmaxf(mx, s[e]);
      float p[8], sum = 0.f;
      #pragma unroll
      for (int e = 0; e < 8; ++e) { p[e] = __expf(s[e] - mx); sum += p[e]; }
      float inv = 1.0f / sum;
      #pragma unroll
      for (int e = 0; e < 8; ++e) p[e] *= inv;
      int i1 = 0;
      #pragma unroll
      for (int e = 1; e < 8; ++e) if (p[e] > p[i1]) i1 = e;
      int i2 = (i1 == 0) ? 1 : 0;
      #pragma unroll
      for (int e = 0; e < 8; ++e) if (e != i1 && p[e] > p[i2]) i2 = e;
      float denom = p[i1] + p[i2] + 1e-9f;
      top2i[2 * token] = i1;            top2i[2 * token + 1] = i2;
      top2w[2 * token] = p[i1] / denom; top2w[2 * token + 1] = p[i2] / denom;
      if (mask[token]) {
        #pragma unroll
        for (int e = 0; e < 8; ++e) atomicAdd(&s_imp[e], p[e]);
        atomicAdd(&s_load[i1], 1.0f);
        atomicAdd(&s_cnt[i1], 1u);
        atomicAdd(&s_cnt[i2], 1u);
        atomicAdd(&s_valid, 1u);
      }
    }
  }
  __syncthreads();
  if (threadIdx.x < 8) {
    if (s_imp[threadIdx.x] != 0.f)  atomicAdd(&ctrl->imp[threadIdx.x], s_imp[threadIdx.x]);
    if (s_load[threadIdx.x] != 0.f) atomicAdd(&ctrl->loadsum[threadIdx.x], s_load[threadIdx.x]);
    if (s_cnt[threadIdx.x])         atomicAdd(&ctrl->cnt[threadIdx.x], s_cnt[threadIdx.x]);
  }
  if (threadIdx.x == 0 && s_valid) atomicAdd(&ctrl->validcnt, (float)s_valid);
}

// ---------------- Offsets (128-aligned segments) + aux loss ----------------
__global__ void finalize_kernel(Ctrl* __restrict__ c, float* __restrict__ auxout)
{
  unsigned o = 0;
  for (int e = 0; e < 8; ++e) { c->off[e] = o; o += (c->cnt[e] + 127u) & ~127u; }
  c->off[8] = o;
  c->used_end = o;
  float cn = fmaxf(c->validcnt, 1.0f);
  float aux = 0.f;
  for (int e = 0; e < 8; ++e) aux += c->imp[e] * c->loadsum[e];
  auxout[0] = aux * 8.0f / (cn * cn);
}

// ---------------- Scatter pairs into per-expert segments ----------------
__global__ __launch_bounds__(256) void scatter_kernel(
    const int* __restrict__ mask, Ctrl* __restrict__ ctrl,
    const int* __restrict__ top2i, const float* __restrict__ top2w,
    int* __restrict__ ptok, float* __restrict__ pwv)
{
  __shared__ unsigned s_cnt[8], s_base[8], s_cur[8];
  if (threadIdx.x < 8) { s_cnt[threadIdx.x] = 0u; s_cur[threadIdx.x] = 0u; }
  __syncthreads();

  int token = blockIdx.x * 256 + threadIdx.x;
  int e0 = -1, e1 = -1; float w0 = 0.f, w1v = 0.f;
  bool valid = (token < NTOK) && mask[token];
  if (valid) {
    e0 = top2i[2 * token];     w0  = top2w[2 * token];
    e1 = top2i[2 * token + 1]; w1v = top2w[2 * token + 1];
    atomicAdd(&s_cnt[e0], 1u);
    atomicAdd(&s_cnt[e1], 1u);
  }
  __syncthreads();
  if (threadIdx.x < 8 && s_cnt[threadIdx.x])
    s_base[threadIdx.x] = ctrl->off[threadIdx.x] +
                          atomicAdd(&ctrl->cursor[threadIdx.x], s_cnt[threadIdx.x]);
  __syncthreads();
  if (valid) {
    unsigned p0 = atomicAdd(&s_cur[e0], 1u);
    unsigned row0 = s_base[e0] + p0;
    ptok[row0] = token; pwv[row0] = w0;
    unsigned p1 = atomicAdd(&s_cur[e1], 1u);
    unsigned row1 = s_base[e1] + p1;
    ptok[row1] = token; pwv[row1] = w1v;
  }
}

// ---------------- Weight chunk converters (fp32 -> bf16, each elem once) ----------------
__global__ __launch_bounds__(256) void convert_w1_kernel(
    const float* __restrict__ src, unsigned short* __restrict__ dst, int hoff, int HC)
{
  unsigned n = (unsigned)NEXP * HC * DDIM;
  unsigned step = gridDim.x * 256 * 8;
  unsigned chsz = (unsigned)HC * DDIM;
  for (unsigned flat = (blockIdx.x * 256 + threadIdx.x) * 8; flat < n; flat += step) {
    unsigned e = flat / chsz;
    const float* s = src + (size_t)flat + (size_t)e * (HDIM - HC) * DDIM + (size_t)hoff * DDIM;
    float4 v0 = ((const float4*)s)[0];
    float4 v1 = ((const float4*)s)[1];
    *(bf16x8*)&dst[flat] = cvt8(v0, v1);
  }
}

__global__ __launch_bounds__(256) void convert_w2_kernel(
    const float* __restrict__ src, unsigned short* __restrict__ dst, int hoff, int HC)
{
  unsigned n = (unsigned)NEXP * DDIM * HC;
  unsigned step = gridDim.x * 256 * 8;
  for (unsigned flat = (blockIdx.x * 256 + threadIdx.x) * 8; flat < n; flat += step) {
    unsigned row = flat / (unsigned)HC;
    const float* s = src + (size_t)flat + (size_t)row * (HDIM - HC) + hoff;
    float4 v0 = ((const float4*)s)[0];
    float4 v1 = ((const float4*)s)[1];
    *(bf16x8*)&dst[flat] = cvt8(v0, v1);
  }
}

// ======== 128x128 tile, BK=64, 4 waves — R7 structure (best anchor) ========
// HC=2048: per-chunk working set (Wbuf 32MB + xb 16MB + Hbuf 67MB) fits the
// 256MB L3, so staging loads hit L2/L3 (~300cy) instead of HBM (~900cy),
// shortening the per-K-tile vmcnt drain that the 4-blocks/CU overlap hides.

#define STAGE8(kt) { \
  _Pragma("unroll") \
  for (int i = 0; i < 4; ++i) { \
    gl_lds16(aRp[i] + (size_t)(kt) * BK, &As[(i * 32 + w * 8) * 64]); \
    gl_lds16(bRp[i] + (size_t)(kt) * BK, &Bs[(i * 32 + w * 8) * 64]); \
  } }

#define KSTEP() { \
  _Pragma("unroll") \
  for (int kk = 0; kk < 2; ++kk) { \
    int rdc = kk ? rd1 : rd0; \
    bf16x8 af[4], bfv[4]; \
    _Pragma("unroll") \
    for (int mi = 0; mi < 4; ++mi) \
      af[mi] = *(const bf16x8*)&As[(wm * 64 + mi * 16 + rl) * 64 + rdc]; \
    _Pragma("unroll") \
    for (int ni = 0; ni < 4; ++ni) \
      bfv[ni] = *(const bf16x8*)&Bs[(wn * 64 + ni * 16 + rl) * 64 + rdc]; \
    _Pragma("unroll") \
    for (int mi = 0; mi < 4; ++mi) \
      _Pragma("unroll") \
      for (int ni = 0; ni < 4; ++ni) \
        acc[mi][ni] = __builtin_amdgcn_mfma_f32_16x16x32_bf16(af[mi], bfv[ni], acc[mi][ni], 0, 0, 0); \
  } }

// ---------------- fc1: H = silu(gather(xb) @ w1b^T + b1) -> bf16 ----------------
__global__ __launch_bounds__(256) void fc1_kernel(
    const unsigned short* __restrict__ xb, const unsigned short* __restrict__ w1b,
    const float* __restrict__ b1, const int* __restrict__ ptok,
    const Ctrl* __restrict__ ctrl, unsigned short* __restrict__ Hbuf,
    int hoff, int HC)
{
  __shared__ __align__(16) short As[8192];
  __shared__ __align__(16) short Bs[8192];

  int nwg = gridDim.x * gridDim.y;
  int id  = blockIdx.y * gridDim.x + blockIdx.x;
  int cpx = nwg >> 3;
  int swz = (id & 7) * cpx + (id >> 3);
  int bx = swz % gridDim.x, by = swz / gridDim.x;

  int m0 = by * 128;
  if ((unsigned)m0 >= ctrl->used_end) return;
  int e = 0;
  #pragma unroll
  for (int i = 1; i < 8; ++i) if ((unsigned)m0 >= ctrl->off[i]) e = i;

  int n0 = bx * 128;
  int t = threadIdx.x, w = t >> 6, l = t & 63;
  int lrow = l >> 3;                         // 0..7
  int sc8 = ((l & 7) ^ lrow) * 8;            // pre-swizzled source chunk (shorts)

  const unsigned short* aRp[4];
  const unsigned short* bRp[4];
  #pragma unroll
  for (int i = 0; i < 4; ++i) {
    int r = i * 32 + w * 8 + lrow;
    int tok = ptok[m0 + r]; if (tok < 0) tok = 0;
    aRp[i] = xb + (size_t)tok * DDIM + sc8;
    bRp[i] = w1b + ((size_t)e * HC + n0 + r) * DDIM + sc8;
  }

  int wm = w >> 1, wn = w & 1, kc = l >> 4, rl = l & 15;
  int rd0 = ((kc)     ^ (rl & 7)) * 8;       // kk=0 read chunk
  int rd1 = ((4 + kc) ^ (rl & 7)) * 8;       // kk=1

  f32x4 acc[4][4] = {};
  const int NK = DDIM / BK;                  // 16

  for (int kt = 0; kt < NK; ++kt) {
    STAGE8(kt);
    __syncthreads();                         // drain -> LDS ready
    KSTEP();
    __syncthreads();                         // reads done before next overwrite
  }

  float b1v[4];
  #pragma unroll
  for (int ni = 0; ni < 4; ++ni)
    b1v[ni] = b1[e * HDIM + hoff + n0 + wn * 64 + ni * 16 + rl];

  #pragma unroll
  for (int mi = 0; mi < 4; ++mi) {
    #pragma unroll
    for (int reg = 0; reg < 4; ++reg) {
      int grow = m0 + wm * 64 + mi * 16 + kc * 4 + reg;
      size_t base = (size_t)grow * HC;
      #pragma unroll
      for (int ni = 0; ni < 4; ++ni) {
        int col = n0 + wn * 64 + ni * 16 + rl;
        float v = acc[mi][ni][reg] + b1v[ni];
        v = v / (1.0f + __expf(-v));
        Hbuf[base + col] = f2bfu(v);
      }
    }
  }
}

// ---------------- fc2: y += w * (Hbuf @ w2b^T + b2), K-split x2 ----------------
__global__ __launch_bounds__(256) void fc2_kernel(
    const unsigned short* __restrict__ Hbuf, const unsigned short* __restrict__ w2b,
    const float* __restrict__ b2, const int* __restrict__ ptok,
    const float* __restrict__ pwv, const Ctrl* __restrict__ ctrl,
    float* __restrict__ y, int hoff, int HC)
{
  __shared__ __align__(16) short As[8192];
  __shared__ __align__(16) short Bs[8192];

  int nwg = gridDim.x * gridDim.y;
  int id  = blockIdx.y * gridDim.x + blockIdx.x;
  int cpx = nwg >> 3;
  int swz = (id & 7) * cpx + (id >> 3);
  int bx = swz % gridDim.x, by = swz / gridDim.x;

  int ntile = bx & 7, kz = bx >> 3;          // gridDim.x = 16: 8 N-tiles x 2 K-splits
  int KLEN = HC >> 1;
  int ksoff = kz * KLEN;

  int m0 = by * 128;
  if ((unsigned)m0 >= ctrl->used_end) return;
  int e = 0;
  #pragma unroll
  for (int i = 1; i < 8; ++i) if ((unsigned)m0 >= ctrl->off[i]) e = i;

  int n0 = ntile * 128;
  int t = threadIdx.x, w = t >> 6, l = t & 63;
  int lrow = l >> 3;
  int sc8 = ((l & 7) ^ lrow) * 8;

  const unsigned short* aRp[4];
  const unsigned short* bRp[4];
  #pragma unroll
  for (int i = 0; i < 4; ++i) {
    int r = i * 32 + w * 8 + lrow;
    aRp[i] = Hbuf + (size_t)(m0 + r) * HC + ksoff + sc8;
    bRp[i] = w2b + ((size_t)e * DDIM + n0 + r) * HC + ksoff + sc8;
  }

  int wm = w >> 1, wn = w & 1, kc = l >> 4, rl = l & 15;
  int rd0 = ((kc)     ^ (rl & 7)) * 8;
  int rd1 = ((4 + kc) ^ (rl & 7)) * 8;

  f32x4 acc[4][4] = {};
  const int NK = KLEN / BK;                  // HC=2048 -> 16

  for (int kt = 0; kt < NK; ++kt) {
    STAGE8(kt);
    __syncthreads();
    KSTEP();
    __syncthreads();
  }

  bool addb = (hoff == 0) && (kz == 0);
  float b2v[4];
  #pragma unroll
  for (int ni = 0; ni < 4; ++ni)
    b2v[ni] = addb ? b2[e * DDIM + n0 + wn * 64 + ni * 16 + rl] : 0.0f;

  #pragma unroll
  for (int mi = 0; mi < 4; ++mi) {
    #pragma unroll
    for (int reg = 0; reg < 4; ++reg) {
      int grow = m0 + wm * 64 + mi * 16 + kc * 4 + reg;
      int tok = ptok[grow];
      if (tok < 0) continue;
      float wgt = pwv[grow];
      float* yrow = y + (size_t)tok * DDIM;
      #pragma unroll
      for (int ni = 0; ni < 4; ++ni) {
        int col = n0 + wn * 64 + ni * 16 + rl;
        atomicAdd(&yrow[col], wgt * (acc[mi][ni][reg] + b2v[ni]));
      }
    }
  }
}

extern "C" void kernel_launch(void* const* d_in, const int* in_sizes, int n_in,
                              void* d_out, int out_size, void* d_ws, size_t ws_size,
                              hipStream_t stream) {
  (void)in_sizes; (void)n_in;
  const float* xp   = (const float*)d_in[0];
  const int*   mkp  = (const int*)d_in[1];
  const float* rwp  = (const float*)d_in[2];
  const float* w1p  = (const float*)d_in[3];
  const float* b1p  = (const float*)d_in[4];
  const float* w2p  = (const float*)d_in[5];
  const float* b2p  = (const float*)d_in[6];

  float* yp   = (float*)d_out;
  float* auxp = (float*)d_out + (out_size - 1);

  char* wsb = (char*)d_ws;
  Ctrl* ctrl = (Ctrl*)wsb;
  int*   top2i = (int*)(wsb + 1024);
  float* top2w = (float*)(wsb + 66560);
  int*   ptok  = (int*)(wsb + 132096);
  float* pwv   = (float*)(wsb + 205824);
  unsigned short* xb   = (unsigned short*)(wsb + 1048576);   // 16 MB
  unsigned short* Wbuf = (unsigned short*)(wsb + 17825792);  // 16384*HC bytes

  // HC=2048: per-chunk working set fits L3 (the R10 lever). Peak ws =
  // 17825792 + 51200*HC = 123 MB (proven available: R3/R7 ran at 227 MB).
  int HC = 2048;
  while (HC > 1024 && ws_size < 17825792ull + 51200ull * (unsigned long long)HC) HC >>= 1;
  int nch = HDIM / HC;
  unsigned short* Hbuf = (unsigned short*)(wsb + 17825792 + (size_t)16384 * HC);

  hipMemsetAsync(d_out, 0, (size_t)out_size * sizeof(float), stream);
  hipMemsetAsync(ctrl, 0, 256, stream);
  hipMemsetAsync(ptok, 0xFF, CAP * sizeof(int), stream);

  router_kernel<<<1024, 256, 0, stream>>>(xp, mkp, rwp, ctrl, top2i, top2w, xb);
  finalize_kernel<<<1, 1, 0, stream>>>(ctrl, auxp);
  scatter_kernel<<<NTOK / 256, 256, 0, stream>>>(mkp, ctrl, top2i, top2w, ptok, pwv);

  for (int c = 0; c < nch; ++c) {
    int hoff = c * HC;
    convert_w1_kernel<<<2048, 256, 0, stream>>>(w1p, Wbuf, hoff, HC);
    fc1_kernel<<<dim3(HC / 128, MT), 256, 0, stream>>>(xb, Wbuf, b1p, ptok, ctrl, Hbuf, hoff, HC);
    convert_w2_kernel<<<2048, 256, 0, stream>>>(w2p, Wbuf, hoff, HC);
    fc2_kernel<<<dim3(16, MT), 256, 0, stream>>>(Hbuf, Wbuf, b2p, ptok, pwv, ctrl, yp, hoff, HC);
  }
}

// Round 11
// 603.460 us; speedup vs baseline: 1.3222x; 1.1957x over previous
//
#include <hip/hip_runtime.h>
#include <hip/hip_bf16.h>

using bf16x8 = __attribute__((ext_vector_type(8))) short;
using f32x4  = __attribute__((ext_vector_type(4))) float;

#define NTOK 8192
#define DDIM 1024
#define NEXP 8
#define HDIM 4096
#define CAP  17408   // 16384 pairs + 8*128 padding
#define MT   136     // CAP / 128 M-tiles (worst case)
#define BK   64

struct Ctrl {
  unsigned cnt[8];
  unsigned cursor[8];
  unsigned off[9];
  unsigned used_end;
  float imp[8];
  float loadsum[8];
  float validcnt;
};

typedef __attribute__((address_space(1))) unsigned GU;
typedef __attribute__((address_space(3))) unsigned LU;
__device__ __forceinline__ void gl_lds16(const unsigned short* g, short* l) {
  __builtin_amdgcn_global_load_lds((const GU*)(g), (LU*)(l), 16, 0, 0);
}

__device__ inline unsigned short f2bfu(float f) {
  __hip_bfloat16 h = __float2bfloat16(f);
  return *reinterpret_cast<unsigned short*>(&h);
}
__device__ inline bf16x8 cvt8(float4 a, float4 b) {
  bf16x8 v;
  v[0] = (short)f2bfu(a.x); v[1] = (short)f2bfu(a.y);
  v[2] = (short)f2bfu(a.z); v[3] = (short)f2bfu(a.w);
  v[4] = (short)f2bfu(b.x); v[5] = (short)f2bfu(b.y);
  v[6] = (short)f2bfu(b.z); v[7] = (short)f2bfu(b.w);
  return v;
}

// ---------------- Router: logits -> softmax -> top2 -> stats; also x -> bf16 ----------------
__global__ __launch_bounds__(256) void router_kernel(
    const float* __restrict__ x, const int* __restrict__ mask,
    const float* __restrict__ rw, Ctrl* __restrict__ ctrl,
    int* __restrict__ top2i, float* __restrict__ top2w,
    unsigned short* __restrict__ xb)
{
  __shared__ float s_imp[8];
  __shared__ float s_load[8];
  __shared__ unsigned s_cnt[8];
  __shared__ unsigned s_valid;
  if (threadIdx.x < 8) { s_imp[threadIdx.x] = 0.f; s_load[threadIdx.x] = 0.f; s_cnt[threadIdx.x] = 0u; }
  if (threadIdx.x == 0) s_valid = 0u;
  __syncthreads();

  int wid = threadIdx.x >> 6, lane = threadIdx.x & 63;

  for (int token = blockIdx.x * 4 + wid; token < NTOK; token += gridDim.x * 4) {
    const float* xr = x + (size_t)token * DDIM + lane * 16;
    float4 x0 = ((const float4*)xr)[0];
    float4 x1 = ((const float4*)xr)[1];
    float4 x2 = ((const float4*)xr)[2];
    float4 x3 = ((const float4*)xr)[3];

    unsigned short* xo = xb + (size_t)token * DDIM + lane * 16;
    *(bf16x8*)xo       = cvt8(x0, x1);
    *(bf16x8*)(xo + 8) = cvt8(x2, x3);

    float s[8];
    #pragma unroll
    for (int e = 0; e < 8; ++e) {
      const float* rp = rw + e * DDIM + lane * 16;
      float4 r0 = ((const float4*)rp)[0];
      float4 r1 = ((const float4*)rp)[1];
      float4 r2 = ((const float4*)rp)[2];
      float4 r3 = ((const float4*)rp)[3];
      float a = x0.x * r0.x;
      a = fmaf(x0.y, r0.y, a); a = fmaf(x0.z, r0.z, a); a = fmaf(x0.w, r0.w, a);
      a = fmaf(x1.x, r1.x, a); a = fmaf(x1.y, r1.y, a); a = fmaf(x1.z, r1.z, a); a = fmaf(x1.w, r1.w, a);
      a = fmaf(x2.x, r2.x, a); a = fmaf(x2.y, r2.y, a); a = fmaf(x2.z, r2.z, a); a = fmaf(x2.w, r2.w, a);
      a = fmaf(x3.x, r3.x, a); a = fmaf(x3.y, r3.y, a); a = fmaf(x3.z, r3.z, a); a = fmaf(x3.w, r3.w, a);
      s[e] = a;
    }
    #pragma unroll
    for (int e = 0; e < 8; ++e)
      #pragma unroll
      for (int o = 32; o; o >>= 1) s[e] += __shfl_xor(s[e], o);

    if (lane == 0) {
      float mx = s[0];
      #pragma unroll
      for (int e = 1; e < 8; ++e) mx = fmaxf(mx, s[e]);
      float p[8], sum = 0.f;
      #pragma unroll
      for (int e = 0; e < 8; ++e) { p[e] = __expf(s[e] - mx); sum += p[e]; }
      float inv = 1.0f / sum;
      #pragma unroll
      for (int e = 0; e < 8; ++e) p[e] *= inv;
      int i1 = 0;
      #pragma unroll
      for (int e = 1; e < 8; ++e) if (p[e] > p[i1]) i1 = e;
      int i2 = (i1 == 0) ? 1 : 0;
      #pragma unroll
      for (int e = 0; e < 8; ++e) if (e != i1 && p[e] > p[i2]) i2 = e;
      float denom = p[i1] + p[i2] + 1e-9f;
      top2i[2 * token] = i1;            top2i[2 * token + 1] = i2;
      top2w[2 * token] = p[i1] / denom; top2w[2 * token + 1] = p[i2] / denom;
      if (mask[token]) {
        #pragma unroll
        for (int e = 0; e < 8; ++e) atomicAdd(&s_imp[e], p[e]);
        atomicAdd(&s_load[i1], 1.0f);
        atomicAdd(&s_cnt[i1], 1u);
        atomicAdd(&s_cnt[i2], 1u);
        atomicAdd(&s_valid, 1u);
      }
    }
  }
  __syncthreads();
  if (threadIdx.x < 8) {
    if (s_imp[threadIdx.x] != 0.f)  atomicAdd(&ctrl->imp[threadIdx.x], s_imp[threadIdx.x]);
    if (s_load[threadIdx.x] != 0.f) atomicAdd(&ctrl->loadsum[threadIdx.x], s_load[threadIdx.x]);
    if (s_cnt[threadIdx.x])         atomicAdd(&ctrl->cnt[threadIdx.x], s_cnt[threadIdx.x]);
  }
  if (threadIdx.x == 0 && s_valid) atomicAdd(&ctrl->validcnt, (float)s_valid);
}

// ---------------- Offsets (128-aligned segments) + aux loss ----------------
__global__ void finalize_kernel(Ctrl* __restrict__ c, float* __restrict__ auxout)
{
  unsigned o = 0;
  for (int e = 0; e < 8; ++e) { c->off[e] = o; o += (c->cnt[e] + 127u) & ~127u; }
  c->off[8] = o;
  c->used_end = o;
  float cn = fmaxf(c->validcnt, 1.0f);
  float aux = 0.f;
  for (int e = 0; e < 8; ++e) aux += c->imp[e] * c->loadsum[e];
  auxout[0] = aux * 8.0f / (cn * cn);
}

// ---------------- Scatter pairs into per-expert segments ----------------
__global__ __launch_bounds__(256) void scatter_kernel(
    const int* __restrict__ mask, Ctrl* __restrict__ ctrl,
    const int* __restrict__ top2i, const float* __restrict__ top2w,
    int* __restrict__ ptok, float* __restrict__ pwv)
{
  __shared__ unsigned s_cnt[8], s_base[8], s_cur[8];
  if (threadIdx.x < 8) { s_cnt[threadIdx.x] = 0u; s_cur[threadIdx.x] = 0u; }
  __syncthreads();

  int token = blockIdx.x * 256 + threadIdx.x;
  int e0 = -1, e1 = -1; float w0 = 0.f, w1v = 0.f;
  bool valid = (token < NTOK) && mask[token];
  if (valid) {
    e0 = top2i[2 * token];     w0  = top2w[2 * token];
    e1 = top2i[2 * token + 1]; w1v = top2w[2 * token + 1];
    atomicAdd(&s_cnt[e0], 1u);
    atomicAdd(&s_cnt[e1], 1u);
  }
  __syncthreads();
  if (threadIdx.x < 8 && s_cnt[threadIdx.x])
    s_base[threadIdx.x] = ctrl->off[threadIdx.x] +
                          atomicAdd(&ctrl->cursor[threadIdx.x], s_cnt[threadIdx.x]);
  __syncthreads();
  if (valid) {
    unsigned p0 = atomicAdd(&s_cur[e0], 1u);
    unsigned row0 = s_base[e0] + p0;
    ptok[row0] = token; pwv[row0] = w0;
    unsigned p1 = atomicAdd(&s_cur[e1], 1u);
    unsigned row1 = s_base[e1] + p1;
    ptok[row1] = token; pwv[row1] = w1v;
  }
}

// ---------------- Weight chunk converters (fp32 -> bf16, each elem once) ----------------
__global__ __launch_bounds__(256) void convert_w1_kernel(
    const float* __restrict__ src, unsigned short* __restrict__ dst, int hoff, int HC)
{
  unsigned n = (unsigned)NEXP * HC * DDIM;
  unsigned step = gridDim.x * 256 * 8;
  unsigned chsz = (unsigned)HC * DDIM;
  for (unsigned flat = (blockIdx.x * 256 + threadIdx.x) * 8; flat < n; flat += step) {
    unsigned e = flat / chsz;
    const float* s = src + (size_t)flat + (size_t)e * (HDIM - HC) * DDIM + (size_t)hoff * DDIM;
    float4 v0 = ((const float4*)s)[0];
    float4 v1 = ((const float4*)s)[1];
    *(bf16x8*)&dst[flat] = cvt8(v0, v1);
  }
}

__global__ __launch_bounds__(256) void convert_w2_kernel(
    const float* __restrict__ src, unsigned short* __restrict__ dst, int hoff, int HC)
{
  unsigned n = (unsigned)NEXP * DDIM * HC;
  unsigned step = gridDim.x * 256 * 8;
  for (unsigned flat = (blockIdx.x * 256 + threadIdx.x) * 8; flat < n; flat += step) {
    unsigned row = flat / (unsigned)HC;
    const float* s = src + (size_t)flat + (size_t)row * (HDIM - HC) + hoff;
    float4 v0 = ((const float4*)s)[0];
    float4 v1 = ((const float4*)s)[1];
    *(bf16x8*)&dst[flat] = cvt8(v0, v1);
  }
}

// ======== 128x128 tile, BK=64, 4 waves — R7 structure (best anchor) ========
// fc1 decodes blocks COLUMN-major so the ~160 concurrently-resident blocks
// per XCD share ~1 N-tile weight panel (~2.4MB, fits 4MB per-XCD L2) instead
// of 32 panels (8-16MB -> L3/HBM thrash = fc1's 317MB FETCH).
// fc2 keeps row-major: its large re-read operand (Hbuf) is row-shared.

#define STAGE8(kt) { \
  _Pragma("unroll") \
  for (int i = 0; i < 4; ++i) { \
    gl_lds16(aRp[i] + (size_t)(kt) * BK, &As[(i * 32 + w * 8) * 64]); \
    gl_lds16(bRp[i] + (size_t)(kt) * BK, &Bs[(i * 32 + w * 8) * 64]); \
  } }

#define KSTEP() { \
  _Pragma("unroll") \
  for (int kk = 0; kk < 2; ++kk) { \
    int rdc = kk ? rd1 : rd0; \
    bf16x8 af[4], bfv[4]; \
    _Pragma("unroll") \
    for (int mi = 0; mi < 4; ++mi) \
      af[mi] = *(const bf16x8*)&As[(wm * 64 + mi * 16 + rl) * 64 + rdc]; \
    _Pragma("unroll") \
    for (int ni = 0; ni < 4; ++ni) \
      bfv[ni] = *(const bf16x8*)&Bs[(wn * 64 + ni * 16 + rl) * 64 + rdc]; \
    _Pragma("unroll") \
    for (int mi = 0; mi < 4; ++mi) \
      _Pragma("unroll") \
      for (int ni = 0; ni < 4; ++ni) \
        acc[mi][ni] = __builtin_amdgcn_mfma_f32_16x16x32_bf16(af[mi], bfv[ni], acc[mi][ni], 0, 0, 0); \
  } }

// ---------------- fc1: H = silu(gather(xb) @ w1b^T + b1) -> bf16 ----------------
__global__ __launch_bounds__(256) void fc1_kernel(
    const unsigned short* __restrict__ xb, const unsigned short* __restrict__ w1b,
    const float* __restrict__ b1, const int* __restrict__ ptok,
    const Ctrl* __restrict__ ctrl, unsigned short* __restrict__ Hbuf,
    int hoff, int HC)
{
  __shared__ __align__(16) short As[8192];
  __shared__ __align__(16) short Bs[8192];

  int nwg = gridDim.x * gridDim.y;
  int id  = blockIdx.y * gridDim.x + blockIdx.x;
  int cpx = nwg >> 3;
  int swz = (id & 7) * cpx + (id >> 3);
  // column-major decode: consecutive swz (same XCD chunk) share bx -> weight panel in L2
  int by = swz % gridDim.y, bx = swz / gridDim.y;

  int m0 = by * 128;
  if ((unsigned)m0 >= ctrl->used_end) return;
  int e = 0;
  #pragma unroll
  for (int i = 1; i < 8; ++i) if ((unsigned)m0 >= ctrl->off[i]) e = i;

  int n0 = bx * 128;
  int t = threadIdx.x, w = t >> 6, l = t & 63;
  int lrow = l >> 3;                         // 0..7
  int sc8 = ((l & 7) ^ lrow) * 8;            // pre-swizzled source chunk (shorts)

  const unsigned short* aRp[4];
  const unsigned short* bRp[4];
  #pragma unroll
  for (int i = 0; i < 4; ++i) {
    int r = i * 32 + w * 8 + lrow;
    int tok = ptok[m0 + r]; if (tok < 0) tok = 0;
    aRp[i] = xb + (size_t)tok * DDIM + sc8;
    bRp[i] = w1b + ((size_t)e * HC + n0 + r) * DDIM + sc8;
  }

  int wm = w >> 1, wn = w & 1, kc = l >> 4, rl = l & 15;
  int rd0 = ((kc)     ^ (rl & 7)) * 8;       // kk=0 read chunk
  int rd1 = ((4 + kc) ^ (rl & 7)) * 8;       // kk=1

  f32x4 acc[4][4] = {};
  const int NK = DDIM / BK;                  // 16

  for (int kt = 0; kt < NK; ++kt) {
    STAGE8(kt);
    __syncthreads();                         // drain -> LDS ready
    KSTEP();
    __syncthreads();                         // reads done before next overwrite
  }

  float b1v[4];
  #pragma unroll
  for (int ni = 0; ni < 4; ++ni)
    b1v[ni] = b1[e * HDIM + hoff + n0 + wn * 64 + ni * 16 + rl];

  #pragma unroll
  for (int mi = 0; mi < 4; ++mi) {
    #pragma unroll
    for (int reg = 0; reg < 4; ++reg) {
      int grow = m0 + wm * 64 + mi * 16 + kc * 4 + reg;
      size_t base = (size_t)grow * HC;
      #pragma unroll
      for (int ni = 0; ni < 4; ++ni) {
        int col = n0 + wn * 64 + ni * 16 + rl;
        float v = acc[mi][ni][reg] + b1v[ni];
        v = v / (1.0f + __expf(-v));
        Hbuf[base + col] = f2bfu(v);
      }
    }
  }
}

// ---------------- fc2: y += w * (Hbuf @ w2b^T + b2), K-split x2 ----------------
__global__ __launch_bounds__(256) void fc2_kernel(
    const unsigned short* __restrict__ Hbuf, const unsigned short* __restrict__ w2b,
    const float* __restrict__ b2, const int* __restrict__ ptok,
    const float* __restrict__ pwv, const Ctrl* __restrict__ ctrl,
    float* __restrict__ y, int hoff, int HC)
{
  __shared__ __align__(16) short As[8192];
  __shared__ __align__(16) short Bs[8192];

  int nwg = gridDim.x * gridDim.y;
  int id  = blockIdx.y * gridDim.x + blockIdx.x;
  int cpx = nwg >> 3;
  int swz = (id & 7) * cpx + (id >> 3);
  int bx = swz % gridDim.x, by = swz / gridDim.x;   // row-major (A=Hbuf shared)

  int ntile = bx & 7, kz = bx >> 3;          // gridDim.x = 16: 8 N-tiles x 2 K-splits
  int KLEN = HC >> 1;
  int ksoff = kz * KLEN;

  int m0 = by * 128;
  if ((unsigned)m0 >= ctrl->used_end) return;
  int e = 0;
  #pragma unroll
  for (int i = 1; i < 8; ++i) if ((unsigned)m0 >= ctrl->off[i]) e = i;

  int n0 = ntile * 128;
  int t = threadIdx.x, w = t >> 6, l = t & 63;
  int lrow = l >> 3;
  int sc8 = ((l & 7) ^ lrow) * 8;

  const unsigned short* aRp[4];
  const unsigned short* bRp[4];
  #pragma unroll
  for (int i = 0; i < 4; ++i) {
    int r = i * 32 + w * 8 + lrow;
    aRp[i] = Hbuf + (size_t)(m0 + r) * HC + ksoff + sc8;
    bRp[i] = w2b + ((size_t)e * DDIM + n0 + r) * HC + ksoff + sc8;
  }

  int wm = w >> 1, wn = w & 1, kc = l >> 4, rl = l & 15;
  int rd0 = ((kc)     ^ (rl & 7)) * 8;
  int rd1 = ((4 + kc) ^ (rl & 7)) * 8;

  f32x4 acc[4][4] = {};
  const int NK = KLEN / BK;                  // HC=4096 -> 32

  for (int kt = 0; kt < NK; ++kt) {
    STAGE8(kt);
    __syncthreads();
    KSTEP();
    __syncthreads();
  }

  bool addb = (hoff == 0) && (kz == 0);
  float b2v[4];
  #pragma unroll
  for (int ni = 0; ni < 4; ++ni)
    b2v[ni] = addb ? b2[e * DDIM + n0 + wn * 64 + ni * 16 + rl] : 0.0f;

  #pragma unroll
  for (int mi = 0; mi < 4; ++mi) {
    #pragma unroll
    for (int reg = 0; reg < 4; ++reg) {
      int grow = m0 + wm * 64 + mi * 16 + kc * 4 + reg;
      int tok = ptok[grow];
      if (tok < 0) continue;
      float wgt = pwv[grow];
      float* yrow = y + (size_t)tok * DDIM;
      #pragma unroll
      for (int ni = 0; ni < 4; ++ni) {
        int col = n0 + wn * 64 + ni * 16 + rl;
        atomicAdd(&yrow[col], wgt * (acc[mi][ni][reg] + b2v[ni]));
      }
    }
  }
}

extern "C" void kernel_launch(void* const* d_in, const int* in_sizes, int n_in,
                              void* d_out, int out_size, void* d_ws, size_t ws_size,
                              hipStream_t stream) {
  (void)in_sizes; (void)n_in;
  const float* xp   = (const float*)d_in[0];
  const int*   mkp  = (const int*)d_in[1];
  const float* rwp  = (const float*)d_in[2];
  const float* w1p  = (const float*)d_in[3];
  const float* b1p  = (const float*)d_in[4];
  const float* w2p  = (const float*)d_in[5];
  const float* b2p  = (const float*)d_in[6];

  float* yp   = (float*)d_out;
  float* auxp = (float*)d_out + (out_size - 1);

  char* wsb = (char*)d_ws;
  Ctrl* ctrl = (Ctrl*)wsb;
  int*   top2i = (int*)(wsb + 1024);
  float* top2w = (float*)(wsb + 66560);
  int*   ptok  = (int*)(wsb + 132096);
  float* pwv   = (float*)(wsb + 205824);
  unsigned short* xb   = (unsigned short*)(wsb + 1048576);   // 16 MB
  unsigned short* Wbuf = (unsigned short*)(wsb + 17825792);  // 16384*HC bytes

  // HC ladder (R7 anchor): peak ws = 17825792 + 51200*HC; HC=4096 proven fits
  int HC = 4096;
  while (HC > 1024 && ws_size < 17825792ull + 51200ull * (unsigned long long)HC) HC >>= 1;
  int nch = HDIM / HC;
  unsigned short* Hbuf = (unsigned short*)(wsb + 17825792 + (size_t)16384 * HC);

  hipMemsetAsync(d_out, 0, (size_t)out_size * sizeof(float), stream);
  hipMemsetAsync(ctrl, 0, 256, stream);
  hipMemsetAsync(ptok, 0xFF, CAP * sizeof(int), stream);

  router_kernel<<<1024, 256, 0, stream>>>(xp, mkp, rwp, ctrl, top2i, top2w, xb);
  finalize_kernel<<<1, 1, 0, stream>>>(ctrl, auxp);
  scatter_kernel<<<NTOK / 256, 256, 0, stream>>>(mkp, ctrl, top2i, top2w, ptok, pwv);

  for (int c = 0; c < nch; ++c) {
    int hoff = c * HC;
    convert_w1_kernel<<<2048, 256, 0, stream>>>(w1p, Wbuf, hoff, HC);
    fc1_kernel<<<dim3(HC / 128, MT), 256, 0, stream>>>(xb, Wbuf, b1p, ptok, ctrl, Hbuf, hoff, HC);
    convert_w2_kernel<<<2048, 256, 0, stream>>>(w2p, Wbuf, hoff, HC);
    fc2_kernel<<<dim3(16, MT), 256, 0, stream>>>(Hbuf, Wbuf, b2p, ptok, pwv, ctrl, yp, hoff, HC);
  }
}

// Round 12
// 582.475 us; speedup vs baseline: 1.3698x; 1.0360x over previous
//
#include <hip/hip_runtime.h>
#include <hip/hip_bf16.h>

using bf16x8 = __attribute__((ext_vector_type(8))) short;
using f32x4  = __attribute__((ext_vector_type(4))) float;

#define NTOK 8192
#define DDIM 1024
#define NEXP 8
#define HDIM 4096
#define CAP  17408   // 16384 pairs + 8*128 padding
#define MT   136     // CAP / 128 M-tiles (worst case)
#define BK   64

struct Ctrl {
  unsigned cnt[8];
  unsigned cursor[8];
  unsigned off[9];
  unsigned used_end;
  float imp[8];
  float loadsum[8];
  float validcnt;
};

typedef __attribute__((address_space(1))) unsigned GU;
typedef __attribute__((address_space(3))) unsigned LU;
__device__ __forceinline__ void gl_lds16(const unsigned short* g, short* l) {
  __builtin_amdgcn_global_load_lds((const GU*)(g), (LU*)(l), 16, 0, 0);
}

__device__ inline unsigned short f2bfu(float f) {
  __hip_bfloat16 h = __float2bfloat16(f);
  return *reinterpret_cast<unsigned short*>(&h);
}
__device__ inline bf16x8 cvt8(float4 a, float4 b) {
  bf16x8 v;
  v[0] = (short)f2bfu(a.x); v[1] = (short)f2bfu(a.y);
  v[2] = (short)f2bfu(a.z); v[3] = (short)f2bfu(a.w);
  v[4] = (short)f2bfu(b.x); v[5] = (short)f2bfu(b.y);
  v[6] = (short)f2bfu(b.z); v[7] = (short)f2bfu(b.w);
  return v;
}

// ---------------- Router: logits -> softmax -> top2 -> stats; also x -> bf16 ----------------
__global__ __launch_bounds__(256) void router_kernel(
    const float* __restrict__ x, const int* __restrict__ mask,
    const float* __restrict__ rw, Ctrl* __restrict__ ctrl,
    int* __restrict__ top2i, float* __restrict__ top2w,
    unsigned short* __restrict__ xb)
{
  __shared__ float s_imp[8];
  __shared__ float s_load[8];
  __shared__ unsigned s_cnt[8];
  __shared__ unsigned s_valid;
  if (threadIdx.x < 8) { s_imp[threadIdx.x] = 0.f; s_load[threadIdx.x] = 0.f; s_cnt[threadIdx.x] = 0u; }
  if (threadIdx.x == 0) s_valid = 0u;
  __syncthreads();

  int wid = threadIdx.x >> 6, lane = threadIdx.x & 63;

  for (int token = blockIdx.x * 4 + wid; token < NTOK; token += gridDim.x * 4) {
    const float* xr = x + (size_t)token * DDIM + lane * 16;
    float4 x0 = ((const float4*)xr)[0];
    float4 x1 = ((const float4*)xr)[1];
    float4 x2 = ((const float4*)xr)[2];
    float4 x3 = ((const float4*)xr)[3];

    unsigned short* xo = xb + (size_t)token * DDIM + lane * 16;
    *(bf16x8*)xo       = cvt8(x0, x1);
    *(bf16x8*)(xo + 8) = cvt8(x2, x3);

    float s[8];
    #pragma unroll
    for (int e = 0; e < 8; ++e) {
      const float* rp = rw + e * DDIM + lane * 16;
      float4 r0 = ((const float4*)rp)[0];
      float4 r1 = ((const float4*)rp)[1];
      float4 r2 = ((const float4*)rp)[2];
      float4 r3 = ((const float4*)rp)[3];
      float a = x0.x * r0.x;
      a = fmaf(x0.y, r0.y, a); a = fmaf(x0.z, r0.z, a); a = fmaf(x0.w, r0.w, a);
      a = fmaf(x1.x, r1.x, a); a = fmaf(x1.y, r1.y, a); a = fmaf(x1.z, r1.z, a); a = fmaf(x1.w, r1.w, a);
      a = fmaf(x2.x, r2.x, a); a = fmaf(x2.y, r2.y, a); a = fmaf(x2.z, r2.z, a); a = fmaf(x2.w, r2.w, a);
      a = fmaf(x3.x, r3.x, a); a = fmaf(x3.y, r3.y, a); a = fmaf(x3.z, r3.z, a); a = fmaf(x3.w, r3.w, a);
      s[e] = a;
    }
    #pragma unroll
    for (int e = 0; e < 8; ++e)
      #pragma unroll
      for (int o = 32; o; o >>= 1) s[e] += __shfl_xor(s[e], o);

    if (lane == 0) {
      float mx = s[0];
      #pragma unroll
      for (int e = 1; e < 8; ++e) mx = fmaxf(mx, s[e]);
      float p[8], sum = 0.f;
      #pragma unroll
      for (int e = 0; e < 8; ++e) { p[e] = __expf(s[e] - mx); sum += p[e]; }
      float inv = 1.0f / sum;
      #pragma unroll
      for (int e = 0; e < 8; ++e) p[e] *= inv;
      int i1 = 0;
      #pragma unroll
      for (int e = 1; e < 8; ++e) if (p[e] > p[i1]) i1 = e;
      int i2 = (i1 == 0) ? 1 : 0;
      #pragma unroll
      for (int e = 0; e < 8; ++e) if (e != i1 && p[e] > p[i2]) i2 = e;
      float denom = p[i1] + p[i2] + 1e-9f;
      top2i[2 * token] = i1;            top2i[2 * token + 1] = i2;
      top2w[2 * token] = p[i1] / denom; top2w[2 * token + 1] = p[i2] / denom;
      if (mask[token]) {
        #pragma unroll
        for (int e = 0; e < 8; ++e) atomicAdd(&s_imp[e], p[e]);
        atomicAdd(&s_load[i1], 1.0f);
        atomicAdd(&s_cnt[i1], 1u);
        atomicAdd(&s_cnt[i2], 1u);
        atomicAdd(&s_valid, 1u);
      }
    }
  }
  __syncthreads();
  if (threadIdx.x < 8) {
    if (s_imp[threadIdx.x] != 0.f)  atomicAdd(&ctrl->imp[threadIdx.x], s_imp[threadIdx.x]);
    if (s_load[threadIdx.x] != 0.f) atomicAdd(&ctrl->loadsum[threadIdx.x], s_load[threadIdx.x]);
    if (s_cnt[threadIdx.x])         atomicAdd(&ctrl->cnt[threadIdx.x], s_cnt[threadIdx.x]);
  }
  if (threadIdx.x == 0 && s_valid) atomicAdd(&ctrl->validcnt, (float)s_valid);
}

// ---------------- Offsets (128-aligned segments) + aux loss ----------------
__global__ void finalize_kernel(Ctrl* __restrict__ c, float* __restrict__ auxout)
{
  unsigned o = 0;
  for (int e = 0; e < 8; ++e) { c->off[e] = o; o += (c->cnt[e] + 127u) & ~127u; }
  c->off[8] = o;
  c->used_end = o;
  float cn = fmaxf(c->validcnt, 1.0f);
  float aux = 0.f;
  for (int e = 0; e < 8; ++e) aux += c->imp[e] * c->loadsum[e];
  auxout[0] = aux * 8.0f / (cn * cn);
}

// ---------------- Scatter pairs into per-expert segments ----------------
__global__ __launch_bounds__(256) void scatter_kernel(
    const int* __restrict__ mask, Ctrl* __restrict__ ctrl,
    const int* __restrict__ top2i, const float* __restrict__ top2w,
    int* __restrict__ ptok, float* __restrict__ pwv)
{
  __shared__ unsigned s_cnt[8], s_base[8], s_cur[8];
  if (threadIdx.x < 8) { s_cnt[threadIdx.x] = 0u; s_cur[threadIdx.x] = 0u; }
  __syncthreads();

  int token = blockIdx.x * 256 + threadIdx.x;
  int e0 = -1, e1 = -1; float w0 = 0.f, w1v = 0.f;
  bool valid = (token < NTOK) && mask[token];
  if (valid) {
    e0 = top2i[2 * token];     w0  = top2w[2 * token];
    e1 = top2i[2 * token + 1]; w1v = top2w[2 * token + 1];
    atomicAdd(&s_cnt[e0], 1u);
    atomicAdd(&s_cnt[e1], 1u);
  }
  __syncthreads();
  if (threadIdx.x < 8 && s_cnt[threadIdx.x])
    s_base[threadIdx.x] = ctrl->off[threadIdx.x] +
                          atomicAdd(&ctrl->cursor[threadIdx.x], s_cnt[threadIdx.x]);
  __syncthreads();
  if (valid) {
    unsigned p0 = atomicAdd(&s_cur[e0], 1u);
    unsigned row0 = s_base[e0] + p0;
    ptok[row0] = token; pwv[row0] = w0;
    unsigned p1 = atomicAdd(&s_cur[e1], 1u);
    unsigned row1 = s_base[e1] + p1;
    ptok[row1] = token; pwv[row1] = w1v;
  }
}

// ---------------- Weight chunk converters (fp32 -> bf16, each elem once) ----------------
__global__ __launch_bounds__(256) void convert_w1_kernel(
    const float* __restrict__ src, unsigned short* __restrict__ dst, int hoff, int HC)
{
  unsigned n = (unsigned)NEXP * HC * DDIM;
  unsigned step = gridDim.x * 256 * 8;
  unsigned chsz = (unsigned)HC * DDIM;
  for (unsigned flat = (blockIdx.x * 256 + threadIdx.x) * 8; flat < n; flat += step) {
    unsigned e = flat / chsz;
    const float* s = src + (size_t)flat + (size_t)e * (HDIM - HC) * DDIM + (size_t)hoff * DDIM;
    float4 v0 = ((const float4*)s)[0];
    float4 v1 = ((const float4*)s)[1];
    *(bf16x8*)&dst[flat] = cvt8(v0, v1);
  }
}

__global__ __launch_bounds__(256) void convert_w2_kernel(
    const float* __restrict__ src, unsigned short* __restrict__ dst, int hoff, int HC)
{
  unsigned n = (unsigned)NEXP * DDIM * HC;
  unsigned step = gridDim.x * 256 * 8;
  for (unsigned flat = (blockIdx.x * 256 + threadIdx.x) * 8; flat < n; flat += step) {
    unsigned row = flat / (unsigned)HC;
    const float* s = src + (size_t)flat + (size_t)row * (HDIM - HC) + hoff;
    float4 v0 = ((const float4*)s)[0];
    float4 v1 = ((const float4*)s)[1];
    *(bf16x8*)&dst[flat] = cvt8(v0, v1);
  }
}

// ======== 128x256 tile, BK=64, 8 waves — R7 schedule, 25% less staging ========
// Staging volume ∝ (1/BM + 1/BN): 128x256 = 0.75x of 128x128. The GEMMs are
// staging-BW-bound on the L2/L3 path (~8.6 TB/s logical at R11), so traffic
// reduction converts ~directly to time. LDS 48KB (A 16 + B 32), 8 waves of
// the same 64x64 wave-tile (acc stays 4x4, no VGPR growth). Same proven
// 2-barrier schedule + XOR involution (0 conflicts since R3).

#define STAGE8(kt) { \
  _Pragma("unroll") \
  for (int i = 0; i < 2; ++i) \
    gl_lds16(aRp[i] + (size_t)(kt) * BK, &As[(i * 64 + w * 8) * 64]); \
  _Pragma("unroll") \
  for (int i = 0; i < 4; ++i) \
    gl_lds16(bRp[i] + (size_t)(kt) * BK, &Bs[(i * 64 + w * 8) * 64]); \
}

#define KSTEP() { \
  _Pragma("unroll") \
  for (int kk = 0; kk < 2; ++kk) { \
    int rdc = kk ? rd1 : rd0; \
    bf16x8 af[4], bfv[4]; \
    _Pragma("unroll") \
    for (int mi = 0; mi < 4; ++mi) \
      af[mi] = *(const bf16x8*)&As[(wm * 64 + mi * 16 + rl) * 64 + rdc]; \
    _Pragma("unroll") \
    for (int ni = 0; ni < 4; ++ni) \
      bfv[ni] = *(const bf16x8*)&Bs[(wn * 64 + ni * 16 + rl) * 64 + rdc]; \
    _Pragma("unroll") \
    for (int mi = 0; mi < 4; ++mi) \
      _Pragma("unroll") \
      for (int ni = 0; ni < 4; ++ni) \
        acc[mi][ni] = __builtin_amdgcn_mfma_f32_16x16x32_bf16(af[mi], bfv[ni], acc[mi][ni], 0, 0, 0); \
  } }

// ---------------- fc1: H = silu(gather(xb) @ w1b^T + b1) -> bf16 ----------------
__global__ __launch_bounds__(512) void fc1_kernel(
    const unsigned short* __restrict__ xb, const unsigned short* __restrict__ w1b,
    const float* __restrict__ b1, const int* __restrict__ ptok,
    const Ctrl* __restrict__ ctrl, unsigned short* __restrict__ Hbuf,
    int hoff, int HC)
{
  __shared__ __align__(16) short As[8192];    // 128 rows x 64
  __shared__ __align__(16) short Bs[16384];   // 256 rows x 64

  int nwg = gridDim.x * gridDim.y;
  int id  = blockIdx.y * gridDim.x + blockIdx.x;
  int cpx = nwg >> 3;
  int swz = (id & 7) * cpx + (id >> 3);
  // column-major decode: consecutive swz (same XCD chunk) share bx -> weight panel in L2
  int by = swz % gridDim.y, bx = swz / gridDim.y;

  int m0 = by * 128;
  if ((unsigned)m0 >= ctrl->used_end) return;
  int e = 0;
  #pragma unroll
  for (int i = 1; i < 8; ++i) if ((unsigned)m0 >= ctrl->off[i]) e = i;

  int n0 = bx * 256;
  int t = threadIdx.x, w = t >> 6, l = t & 63;
  int lrow = l >> 3;                         // 0..7
  int sc8 = ((l & 7) ^ lrow) * 8;            // pre-swizzled source chunk (shorts)

  const unsigned short* aRp[2];
  const unsigned short* bRp[4];
  #pragma unroll
  for (int i = 0; i < 2; ++i) {
    int r = i * 64 + w * 8 + lrow;           // A rows 0..127
    int tok = ptok[m0 + r]; if (tok < 0) tok = 0;
    aRp[i] = xb + (size_t)tok * DDIM + sc8;
  }
  #pragma unroll
  for (int i = 0; i < 4; ++i) {
    int r = i * 64 + w * 8 + lrow;           // B rows 0..255
    bRp[i] = w1b + ((size_t)e * HC + n0 + r) * DDIM + sc8;
  }

  int wm = w >> 2, wn = w & 3, kc = l >> 4, rl = l & 15;
  int rd0 = ((kc)     ^ (rl & 7)) * 8;       // kk=0 read chunk
  int rd1 = ((4 + kc) ^ (rl & 7)) * 8;       // kk=1

  f32x4 acc[4][4] = {};
  const int NK = DDIM / BK;                  // 16

  for (int kt = 0; kt < NK; ++kt) {
    STAGE8(kt);
    __syncthreads();                         // drain -> LDS ready
    KSTEP();
    __syncthreads();                         // reads done before next overwrite
  }

  float b1v[4];
  #pragma unroll
  for (int ni = 0; ni < 4; ++ni)
    b1v[ni] = b1[e * HDIM + hoff + n0 + wn * 64 + ni * 16 + rl];

  #pragma unroll
  for (int mi = 0; mi < 4; ++mi) {
    #pragma unroll
    for (int reg = 0; reg < 4; ++reg) {
      int grow = m0 + wm * 64 + mi * 16 + kc * 4 + reg;
      size_t base = (size_t)grow * HC;
      #pragma unroll
      for (int ni = 0; ni < 4; ++ni) {
        int col = n0 + wn * 64 + ni * 16 + rl;
        float v = acc[mi][ni][reg] + b1v[ni];
        v = v / (1.0f + __expf(-v));
        Hbuf[base + col] = f2bfu(v);
      }
    }
  }
}

// ---------------- fc2: y += w * (Hbuf @ w2b^T + b2), K-split x2 ----------------
__global__ __launch_bounds__(512) void fc2_kernel(
    const unsigned short* __restrict__ Hbuf, const unsigned short* __restrict__ w2b,
    const float* __restrict__ b2, const int* __restrict__ ptok,
    const float* __restrict__ pwv, const Ctrl* __restrict__ ctrl,
    float* __restrict__ y, int hoff, int HC)
{
  __shared__ __align__(16) short As[8192];    // 128 rows x 64 (Hbuf)
  __shared__ __align__(16) short Bs[16384];   // 256 rows x 64 (w2b)

  int nwg = gridDim.x * gridDim.y;
  int id  = blockIdx.y * gridDim.x + blockIdx.x;
  int cpx = nwg >> 3;
  int swz = (id & 7) * cpx + (id >> 3);
  int bx = swz % gridDim.x, by = swz / gridDim.x;   // row-major (A=Hbuf shared)

  int ntile = bx & 3, kz = bx >> 2;          // gridDim.x = 8: 4 N-tiles x 2 K-splits
  int KLEN = HC >> 1;
  int ksoff = kz * KLEN;

  int m0 = by * 128;
  if ((unsigned)m0 >= ctrl->used_end) return;
  int e = 0;
  #pragma unroll
  for (int i = 1; i < 8; ++i) if ((unsigned)m0 >= ctrl->off[i]) e = i;

  int n0 = ntile * 256;
  int t = threadIdx.x, w = t >> 6, l = t & 63;
  int lrow = l >> 3;
  int sc8 = ((l & 7) ^ lrow) * 8;

  const unsigned short* aRp[2];
  const unsigned short* bRp[4];
  #pragma unroll
  for (int i = 0; i < 2; ++i) {
    int r = i * 64 + w * 8 + lrow;
    aRp[i] = Hbuf + (size_t)(m0 + r) * HC + ksoff + sc8;
  }
  #pragma unroll
  for (int i = 0; i < 4; ++i) {
    int r = i * 64 + w * 8 + lrow;
    bRp[i] = w2b + ((size_t)e * DDIM + n0 + r) * HC + ksoff + sc8;
  }

  int wm = w >> 2, wn = w & 3, kc = l >> 4, rl = l & 15;
  int rd0 = ((kc)     ^ (rl & 7)) * 8;
  int rd1 = ((4 + kc) ^ (rl & 7)) * 8;

  f32x4 acc[4][4] = {};
  const int NK = KLEN / BK;                  // HC=4096 -> 32

  for (int kt = 0; kt < NK; ++kt) {
    STAGE8(kt);
    __syncthreads();
    KSTEP();
    __syncthreads();
  }

  bool addb = (hoff == 0) && (kz == 0);
  float b2v[4];
  #pragma unroll
  for (int ni = 0; ni < 4; ++ni)
    b2v[ni] = addb ? b2[e * DDIM + n0 + wn * 64 + ni * 16 + rl] : 0.0f;

  #pragma unroll
  for (int mi = 0; mi < 4; ++mi) {
    #pragma unroll
    for (int reg = 0; reg < 4; ++reg) {
      int grow = m0 + wm * 64 + mi * 16 + kc * 4 + reg;
      int tok = ptok[grow];
      if (tok < 0) continue;
      float wgt = pwv[grow];
      float* yrow = y + (size_t)tok * DDIM;
      #pragma unroll
      for (int ni = 0; ni < 4; ++ni) {
        int col = n0 + wn * 64 + ni * 16 + rl;
        atomicAdd(&yrow[col], wgt * (acc[mi][ni][reg] + b2v[ni]));
      }
    }
  }
}

extern "C" void kernel_launch(void* const* d_in, const int* in_sizes, int n_in,
                              void* d_out, int out_size, void* d_ws, size_t ws_size,
                              hipStream_t stream) {
  (void)in_sizes; (void)n_in;
  const float* xp   = (const float*)d_in[0];
  const int*   mkp  = (const int*)d_in[1];
  const float* rwp  = (const float*)d_in[2];
  const float* w1p  = (const float*)d_in[3];
  const float* b1p  = (const float*)d_in[4];
  const float* w2p  = (const float*)d_in[5];
  const float* b2p  = (const float*)d_in[6];

  float* yp   = (float*)d_out;
  float* auxp = (float*)d_out + (out_size - 1);

  char* wsb = (char*)d_ws;
  Ctrl* ctrl = (Ctrl*)wsb;
  int*   top2i = (int*)(wsb + 1024);
  float* top2w = (float*)(wsb + 66560);
  int*   ptok  = (int*)(wsb + 132096);
  float* pwv   = (float*)(wsb + 205824);
  unsigned short* xb   = (unsigned short*)(wsb + 1048576);   // 16 MB
  unsigned short* Wbuf = (unsigned short*)(wsb + 17825792);  // 16384*HC bytes

  // HC ladder (R7 anchor): peak ws = 17825792 + 51200*HC; HC=4096 proven fits
  int HC = 4096;
  while (HC > 1024 && ws_size < 17825792ull + 51200ull * (unsigned long long)HC) HC >>= 1;
  int nch = HDIM / HC;
  unsigned short* Hbuf = (unsigned short*)(wsb + 17825792 + (size_t)16384 * HC);

  hipMemsetAsync(d_out, 0, (size_t)out_size * sizeof(float), stream);
  hipMemsetAsync(ctrl, 0, 256, stream);
  hipMemsetAsync(ptok, 0xFF, CAP * sizeof(int), stream);

  router_kernel<<<1024, 256, 0, stream>>>(xp, mkp, rwp, ctrl, top2i, top2w, xb);
  finalize_kernel<<<1, 1, 0, stream>>>(ctrl, auxp);
  scatter_kernel<<<NTOK / 256, 256, 0, stream>>>(mkp, ctrl, top2i, top2w, ptok, pwv);

  for (int c = 0; c < nch; ++c) {
    int hoff = c * HC;
    convert_w1_kernel<<<2048, 256, 0, stream>>>(w1p, Wbuf, hoff, HC);
    fc1_kernel<<<dim3(HC / 256, MT), 512, 0, stream>>>(xb, Wbuf, b1p, ptok, ctrl, Hbuf, hoff, HC);
    convert_w2_kernel<<<2048, 256, 0, stream>>>(w2p, Wbuf, hoff, HC);
    fc2_kernel<<<dim3(8, MT), 512, 0, stream>>>(Hbuf, Wbuf, b2p, ptok, pwv, ctrl, yp, hoff, HC);
  }
}

// Round 13
// 571.356 us; speedup vs baseline: 1.3965x; 1.0195x over previous
//
#include <hip/hip_runtime.h>
#include <hip/hip_bf16.h>

using bf16x8 = __attribute__((ext_vector_type(8))) short;
using f32x4  = __attribute__((ext_vector_type(4))) float;

#define NTOK 8192
#define DDIM 1024
#define NEXP 8
#define HDIM 4096
#define CAP  17408   // 16384 pairs + 8*128 padding
#define MT   136     // CAP / 128 M-tiles (worst case)
#define BK   64

struct Ctrl {
  unsigned cnt[8];
  unsigned cursor[8];
  unsigned off[9];
  unsigned used_end;
  float imp[8];
  float loadsum[8];
  float validcnt;
};

typedef __attribute__((address_space(1))) unsigned GU;
typedef __attribute__((address_space(3))) unsigned LU;
__device__ __forceinline__ void gl_lds16(const unsigned short* g, short* l) {
  __builtin_amdgcn_global_load_lds((const GU*)(g), (LU*)(l), 16, 0, 0);
}

__device__ inline unsigned short f2bfu(float f) {
  __hip_bfloat16 h = __float2bfloat16(f);
  return *reinterpret_cast<unsigned short*>(&h);
}
__device__ inline bf16x8 cvt8(float4 a, float4 b) {
  bf16x8 v;
  v[0] = (short)f2bfu(a.x); v[1] = (short)f2bfu(a.y);
  v[2] = (short)f2bfu(a.z); v[3] = (short)f2bfu(a.w);
  v[4] = (short)f2bfu(b.x); v[5] = (short)f2bfu(b.y);
  v[6] = (short)f2bfu(b.z); v[7] = (short)f2bfu(b.w);
  return v;
}

// ---------------- Router: logits -> softmax -> top2 -> stats; also x -> bf16 ----------------
__global__ __launch_bounds__(256) void router_kernel(
    const float* __restrict__ x, const int* __restrict__ mask,
    const float* __restrict__ rw, Ctrl* __restrict__ ctrl,
    int* __restrict__ top2i, float* __restrict__ top2w,
    unsigned short* __restrict__ xb)
{
  __shared__ float s_imp[8];
  __shared__ float s_load[8];
  __shared__ unsigned s_cnt[8];
  __shared__ unsigned s_valid;
  if (threadIdx.x < 8) { s_imp[threadIdx.x] = 0.f; s_load[threadIdx.x] = 0.f; s_cnt[threadIdx.x] = 0u; }
  if (threadIdx.x == 0) s_valid = 0u;
  __syncthreads();

  int wid = threadIdx.x >> 6, lane = threadIdx.x & 63;

  for (int token = blockIdx.x * 4 + wid; token < NTOK; token += gridDim.x * 4) {
    const float* xr = x + (size_t)token * DDIM + lane * 16;
    float4 x0 = ((const float4*)xr)[0];
    float4 x1 = ((const float4*)xr)[1];
    float4 x2 = ((const float4*)xr)[2];
    float4 x3 = ((const float4*)xr)[3];

    unsigned short* xo = xb + (size_t)token * DDIM + lane * 16;
    *(bf16x8*)xo       = cvt8(x0, x1);
    *(bf16x8*)(xo + 8) = cvt8(x2, x3);

    float s[8];
    #pragma unroll
    for (int e = 0; e < 8; ++e) {
      const float* rp = rw + e * DDIM + lane * 16;
      float4 r0 = ((const float4*)rp)[0];
      float4 r1 = ((const float4*)rp)[1];
      float4 r2 = ((const float4*)rp)[2];
      float4 r3 = ((const float4*)rp)[3];
      float a = x0.x * r0.x;
      a = fmaf(x0.y, r0.y, a); a = fmaf(x0.z, r0.z, a); a = fmaf(x0.w, r0.w, a);
      a = fmaf(x1.x, r1.x, a); a = fmaf(x1.y, r1.y, a); a = fmaf(x1.z, r1.z, a); a = fmaf(x1.w, r1.w, a);
      a = fmaf(x2.x, r2.x, a); a = fmaf(x2.y, r2.y, a); a = fmaf(x2.z, r2.z, a); a = fmaf(x2.w, r2.w, a);
      a = fmaf(x3.x, r3.x, a); a = fmaf(x3.y, r3.y, a); a = fmaf(x3.z, r3.z, a); a = fmaf(x3.w, r3.w, a);
      s[e] = a;
    }
    #pragma unroll
    for (int e = 0; e < 8; ++e)
      #pragma unroll
      for (int o = 32; o; o >>= 1) s[e] += __shfl_xor(s[e], o);

    if (lane == 0) {
      float mx = s[0];
      #pragma unroll
      for (int e = 1; e < 8; ++e) mx = fmaxf(mx, s[e]);
      float p[8], sum = 0.f;
      #pragma unroll
      for (int e = 0; e < 8; ++e) { p[e] = __expf(s[e] - mx); sum += p[e]; }
      float inv = 1.0f / sum;
      #pragma unroll
      for (int e = 0; e < 8; ++e) p[e] *= inv;
      int i1 = 0;
      #pragma unroll
      for (int e = 1; e < 8; ++e) if (p[e] > p[i1]) i1 = e;
      int i2 = (i1 == 0) ? 1 : 0;
      #pragma unroll
      for (int e = 0; e < 8; ++e) if (e != i1 && p[e] > p[i2]) i2 = e;
      float denom = p[i1] + p[i2] + 1e-9f;
      top2i[2 * token] = i1;            top2i[2 * token + 1] = i2;
      top2w[2 * token] = p[i1] / denom; top2w[2 * token + 1] = p[i2] / denom;
      if (mask[token]) {
        #pragma unroll
        for (int e = 0; e < 8; ++e) atomicAdd(&s_imp[e], p[e]);
        atomicAdd(&s_load[i1], 1.0f);
        atomicAdd(&s_cnt[i1], 1u);
        atomicAdd(&s_cnt[i2], 1u);
        atomicAdd(&s_valid, 1u);
      }
    }
  }
  __syncthreads();
  if (threadIdx.x < 8) {
    if (s_imp[threadIdx.x] != 0.f)  atomicAdd(&ctrl->imp[threadIdx.x], s_imp[threadIdx.x]);
    if (s_load[threadIdx.x] != 0.f) atomicAdd(&ctrl->loadsum[threadIdx.x], s_load[threadIdx.x]);
    if (s_cnt[threadIdx.x])         atomicAdd(&ctrl->cnt[threadIdx.x], s_cnt[threadIdx.x]);
  }
  if (threadIdx.x == 0 && s_valid) atomicAdd(&ctrl->validcnt, (float)s_valid);
}

// ---------------- Offsets (128-aligned segments) + aux loss ----------------
__global__ void finalize_kernel(Ctrl* __restrict__ c, float* __restrict__ auxout)
{
  unsigned o = 0;
  for (int e = 0; e < 8; ++e) { c->off[e] = o; o += (c->cnt[e] + 127u) & ~127u; }
  c->off[8] = o;
  c->used_end = o;
  float cn = fmaxf(c->validcnt, 1.0f);
  float aux = 0.f;
  for (int e = 0; e < 8; ++e) aux += c->imp[e] * c->loadsum[e];
  auxout[0] = aux * 8.0f / (cn * cn);
}

// ---------------- Scatter pairs into per-expert segments ----------------
__global__ __launch_bounds__(256) void scatter_kernel(
    const int* __restrict__ mask, Ctrl* __restrict__ ctrl,
    const int* __restrict__ top2i, const float* __restrict__ top2w,
    int* __restrict__ ptok, float* __restrict__ pwv)
{
  __shared__ unsigned s_cnt[8], s_base[8], s_cur[8];
  if (threadIdx.x < 8) { s_cnt[threadIdx.x] = 0u; s_cur[threadIdx.x] = 0u; }
  __syncthreads();

  int token = blockIdx.x * 256 + threadIdx.x;
  int e0 = -1, e1 = -1; float w0 = 0.f, w1v = 0.f;
  bool valid = (token < NTOK) && mask[token];
  if (valid) {
    e0 = top2i[2 * token];     w0  = top2w[2 * token];
    e1 = top2i[2 * token + 1]; w1v = top2w[2 * token + 1];
    atomicAdd(&s_cnt[e0], 1u);
    atomicAdd(&s_cnt[e1], 1u);
  }
  __syncthreads();
  if (threadIdx.x < 8 && s_cnt[threadIdx.x])
    s_base[threadIdx.x] = ctrl->off[threadIdx.x] +
                          atomicAdd(&ctrl->cursor[threadIdx.x], s_cnt[threadIdx.x]);
  __syncthreads();
  if (valid) {
    unsigned p0 = atomicAdd(&s_cur[e0], 1u);
    unsigned row0 = s_base[e0] + p0;
    ptok[row0] = token; pwv[row0] = w0;
    unsigned p1 = atomicAdd(&s_cur[e1], 1u);
    unsigned row1 = s_base[e1] + p1;
    ptok[row1] = token; pwv[row1] = w1v;
  }
}

// ---------------- Weight chunk converters (fp32 -> bf16, each elem once) ----------------
__global__ __launch_bounds__(256) void convert_w1_kernel(
    const float* __restrict__ src, unsigned short* __restrict__ dst, int hoff, int HC)
{
  unsigned n = (unsigned)NEXP * HC * DDIM;
  unsigned step = gridDim.x * 256 * 8;
  unsigned chsz = (unsigned)HC * DDIM;
  for (unsigned flat = (blockIdx.x * 256 + threadIdx.x) * 8; flat < n; flat += step) {
    unsigned e = flat / chsz;
    const float* s = src + (size_t)flat + (size_t)e * (HDIM - HC) * DDIM + (size_t)hoff * DDIM;
    float4 v0 = ((const float4*)s)[0];
    float4 v1 = ((const float4*)s)[1];
    *(bf16x8*)&dst[flat] = cvt8(v0, v1);
  }
}

__global__ __launch_bounds__(256) void convert_w2_kernel(
    const float* __restrict__ src, unsigned short* __restrict__ dst, int hoff, int HC)
{
  unsigned n = (unsigned)NEXP * DDIM * HC;
  unsigned step = gridDim.x * 256 * 8;
  for (unsigned flat = (blockIdx.x * 256 + threadIdx.x) * 8; flat < n; flat += step) {
    unsigned row = flat / (unsigned)HC;
    const float* s = src + (size_t)flat + (size_t)row * (HDIM - HC) + hoff;
    float4 v0 = ((const float4*)s)[0];
    float4 v1 = ((const float4*)s)[1];
    *(bf16x8*)&dst[flat] = cvt8(v0, v1);
  }
}

// ======== fc1: 128x256 tile (R12-proven, 657 TF). fc2: 128x128 (R11-proven). ========
// Both staging-BW-bound on the L2/L3 path; each GEMM keeps its measured-best
// tile. Same 2-barrier schedule + XOR involution (0 conflicts since R3).

// ---------------- fc1: H = silu(gather(xb) @ w1b^T + b1) -> bf16 ----------------
#define STAGE_F1(kt) { \
  _Pragma("unroll") \
  for (int i = 0; i < 2; ++i) \
    gl_lds16(aRp[i] + (size_t)(kt) * BK, &As[(i * 64 + w * 8) * 64]); \
  _Pragma("unroll") \
  for (int i = 0; i < 4; ++i) \
    gl_lds16(bRp[i] + (size_t)(kt) * BK, &Bs[(i * 64 + w * 8) * 64]); \
}

#define KSTEP_GEN() { \
  _Pragma("unroll") \
  for (int kk = 0; kk < 2; ++kk) { \
    int rdc = kk ? rd1 : rd0; \
    bf16x8 af[4], bfv[4]; \
    _Pragma("unroll") \
    for (int mi = 0; mi < 4; ++mi) \
      af[mi] = *(const bf16x8*)&As[(wm * 64 + mi * 16 + rl) * 64 + rdc]; \
    _Pragma("unroll") \
    for (int ni = 0; ni < 4; ++ni) \
      bfv[ni] = *(const bf16x8*)&Bs[(wn * 64 + ni * 16 + rl) * 64 + rdc]; \
    _Pragma("unroll") \
    for (int mi = 0; mi < 4; ++mi) \
      _Pragma("unroll") \
      for (int ni = 0; ni < 4; ++ni) \
        acc[mi][ni] = __builtin_amdgcn_mfma_f32_16x16x32_bf16(af[mi], bfv[ni], acc[mi][ni], 0, 0, 0); \
  } }

__global__ __launch_bounds__(512) void fc1_kernel(
    const unsigned short* __restrict__ xb, const unsigned short* __restrict__ w1b,
    const float* __restrict__ b1, const int* __restrict__ ptok,
    const Ctrl* __restrict__ ctrl, unsigned short* __restrict__ Hbuf,
    int hoff, int HC)
{
  __shared__ __align__(16) short As[8192];    // 128 rows x 64
  __shared__ __align__(16) short Bs[16384];   // 256 rows x 64

  int nwg = gridDim.x * gridDim.y;
  int id  = blockIdx.y * gridDim.x + blockIdx.x;
  int cpx = nwg >> 3;
  int swz = (id & 7) * cpx + (id >> 3);
  // column-major decode: consecutive swz (same XCD chunk) share bx -> weight panel in L2
  int by = swz % gridDim.y, bx = swz / gridDim.y;

  int m0 = by * 128;
  if ((unsigned)m0 >= ctrl->used_end) return;
  int e = 0;
  #pragma unroll
  for (int i = 1; i < 8; ++i) if ((unsigned)m0 >= ctrl->off[i]) e = i;

  int n0 = bx * 256;
  int t = threadIdx.x, w = t >> 6, l = t & 63;
  int lrow = l >> 3;                         // 0..7
  int sc8 = ((l & 7) ^ lrow) * 8;            // pre-swizzled source chunk (shorts)

  const unsigned short* aRp[2];
  const unsigned short* bRp[4];
  #pragma unroll
  for (int i = 0; i < 2; ++i) {
    int r = i * 64 + w * 8 + lrow;           // A rows 0..127
    int tok = ptok[m0 + r]; if (tok < 0) tok = 0;
    aRp[i] = xb + (size_t)tok * DDIM + sc8;
  }
  #pragma unroll
  for (int i = 0; i < 4; ++i) {
    int r = i * 64 + w * 8 + lrow;           // B rows 0..255
    bRp[i] = w1b + ((size_t)e * HC + n0 + r) * DDIM + sc8;
  }

  int wm = w >> 2, wn = w & 3, kc = l >> 4, rl = l & 15;
  int rd0 = ((kc)     ^ (rl & 7)) * 8;       // kk=0 read chunk
  int rd1 = ((4 + kc) ^ (rl & 7)) * 8;       // kk=1

  f32x4 acc[4][4] = {};
  const int NK = DDIM / BK;                  // 16

  for (int kt = 0; kt < NK; ++kt) {
    STAGE_F1(kt);
    __syncthreads();                         // drain -> LDS ready
    KSTEP_GEN();
    __syncthreads();                         // reads done before next overwrite
  }

  float b1v[4];
  #pragma unroll
  for (int ni = 0; ni < 4; ++ni)
    b1v[ni] = b1[e * HDIM + hoff + n0 + wn * 64 + ni * 16 + rl];

  #pragma unroll
  for (int mi = 0; mi < 4; ++mi) {
    #pragma unroll
    for (int reg = 0; reg < 4; ++reg) {
      int grow = m0 + wm * 64 + mi * 16 + kc * 4 + reg;
      size_t base = (size_t)grow * HC;
      #pragma unroll
      for (int ni = 0; ni < 4; ++ni) {
        int col = n0 + wn * 64 + ni * 16 + rl;
        float v = acc[mi][ni][reg] + b1v[ni];
        v = v / (1.0f + __expf(-v));
        Hbuf[base + col] = f2bfu(v);
      }
    }
  }
}

// ---------------- fc2: y += w * (Hbuf @ w2b^T + b2), 128x128, K-split x2 ----------------
#define STAGE_F2(kt) { \
  _Pragma("unroll") \
  for (int i = 0; i < 4; ++i) { \
    gl_lds16(aRp[i] + (size_t)(kt) * BK, &As[(i * 32 + w * 8) * 64]); \
    gl_lds16(bRp[i] + (size_t)(kt) * BK, &Bs[(i * 32 + w * 8) * 64]); \
  } }

__global__ __launch_bounds__(256) void fc2_kernel(
    const unsigned short* __restrict__ Hbuf, const unsigned short* __restrict__ w2b,
    const float* __restrict__ b2, const int* __restrict__ ptok,
    const float* __restrict__ pwv, const Ctrl* __restrict__ ctrl,
    float* __restrict__ y, int hoff, int HC)
{
  __shared__ __align__(16) short As[8192];
  __shared__ __align__(16) short Bs[8192];

  int nwg = gridDim.x * gridDim.y;
  int id  = blockIdx.y * gridDim.x + blockIdx.x;
  int cpx = nwg >> 3;
  int swz = (id & 7) * cpx + (id >> 3);
  int bx = swz % gridDim.x, by = swz / gridDim.x;   // row-major (A=Hbuf shared)

  int ntile = bx & 7, kz = bx >> 3;          // gridDim.x = 16: 8 N-tiles x 2 K-splits
  int KLEN = HC >> 1;
  int ksoff = kz * KLEN;

  int m0 = by * 128;
  if ((unsigned)m0 >= ctrl->used_end) return;
  int e = 0;
  #pragma unroll
  for (int i = 1; i < 8; ++i) if ((unsigned)m0 >= ctrl->off[i]) e = i;

  int n0 = ntile * 128;
  int t = threadIdx.x, w = t >> 6, l = t & 63;
  int lrow = l >> 3;
  int sc8 = ((l & 7) ^ lrow) * 8;

  const unsigned short* aRp[4];
  const unsigned short* bRp[4];
  #pragma unroll
  for (int i = 0; i < 4; ++i) {
    int r = i * 32 + w * 8 + lrow;
    aRp[i] = Hbuf + (size_t)(m0 + r) * HC + ksoff + sc8;
    bRp[i] = w2b + ((size_t)e * DDIM + n0 + r) * HC + ksoff + sc8;
  }

  int wm = w >> 1, wn = w & 1, kc = l >> 4, rl = l & 15;
  int rd0 = ((kc)     ^ (rl & 7)) * 8;
  int rd1 = ((4 + kc) ^ (rl & 7)) * 8;

  f32x4 acc[4][4] = {};
  const int NK = KLEN / BK;                  // HC=4096 -> 32

  for (int kt = 0; kt < NK; ++kt) {
    STAGE_F2(kt);
    __syncthreads();
    KSTEP_GEN();
    __syncthreads();
  }

  bool addb = (hoff == 0) && (kz == 0);
  float b2v[4];
  #pragma unroll
  for (int ni = 0; ni < 4; ++ni)
    b2v[ni] = addb ? b2[e * DDIM + n0 + wn * 64 + ni * 16 + rl] : 0.0f;

  #pragma unroll
  for (int mi = 0; mi < 4; ++mi) {
    #pragma unroll
    for (int reg = 0; reg < 4; ++reg) {
      int grow = m0 + wm * 64 + mi * 16 + kc * 4 + reg;
      int tok = ptok[grow];
      if (tok < 0) continue;
      float wgt = pwv[grow];
      float* yrow = y + (size_t)tok * DDIM;
      #pragma unroll
      for (int ni = 0; ni < 4; ++ni) {
        int col = n0 + wn * 64 + ni * 16 + rl;
        atomicAdd(&yrow[col], wgt * (acc[mi][ni][reg] + b2v[ni]));
      }
    }
  }
}

extern "C" void kernel_launch(void* const* d_in, const int* in_sizes, int n_in,
                              void* d_out, int out_size, void* d_ws, size_t ws_size,
                              hipStream_t stream) {
  (void)in_sizes; (void)n_in;
  const float* xp   = (const float*)d_in[0];
  const int*   mkp  = (const int*)d_in[1];
  const float* rwp  = (const float*)d_in[2];
  const float* w1p  = (const float*)d_in[3];
  const float* b1p  = (const float*)d_in[4];
  const float* w2p  = (const float*)d_in[5];
  const float* b2p  = (const float*)d_in[6];

  float* yp   = (float*)d_out;
  float* auxp = (float*)d_out + (out_size - 1);

  char* wsb = (char*)d_ws;
  Ctrl* ctrl = (Ctrl*)wsb;
  int*   top2i = (int*)(wsb + 1024);
  float* top2w = (float*)(wsb + 66560);
  int*   ptok  = (int*)(wsb + 132096);
  float* pwv   = (float*)(wsb + 205824);
  unsigned short* xb   = (unsigned short*)(wsb + 1048576);   // 16 MB
  unsigned short* Wbuf = (unsigned short*)(wsb + 17825792);  // 16384*HC bytes

  // HC ladder: peak ws = 17825792 + 51200*HC; HC=4096 proven fits
  int HC = 4096;
  while (HC > 1024 && ws_size < 17825792ull + 51200ull * (unsigned long long)HC) HC >>= 1;
  int nch = HDIM / HC;
  unsigned short* Hbuf = (unsigned short*)(wsb + 17825792 + (size_t)16384 * HC);

  hipMemsetAsync(d_out, 0, (size_t)out_size * sizeof(float), stream);
  hipMemsetAsync(ctrl, 0, 256, stream);
  hipMemsetAsync(ptok, 0xFF, CAP * sizeof(int), stream);

  router_kernel<<<1024, 256, 0, stream>>>(xp, mkp, rwp, ctrl, top2i, top2w, xb);
  finalize_kernel<<<1, 1, 0, stream>>>(ctrl, auxp);
  scatter_kernel<<<NTOK / 256, 256, 0, stream>>>(mkp, ctrl, top2i, top2w, ptok, pwv);

  for (int c = 0; c < nch; ++c) {
    int hoff = c * HC;
    convert_w1_kernel<<<2048, 256, 0, stream>>>(w1p, Wbuf, hoff, HC);
    fc1_kernel<<<dim3(HC / 256, MT), 512, 0, stream>>>(xb, Wbuf, b1p, ptok, ctrl, Hbuf, hoff, HC);
    convert_w2_kernel<<<2048, 256, 0, stream>>>(w2p, Wbuf, hoff, HC);
    fc2_kernel<<<dim3(16, MT), 256, 0, stream>>>(Hbuf, Wbuf, b2p, ptok, pwv, ctrl, yp, hoff, HC);
  }
}